// Round 16
// baseline (1202.969 us; speedup 1.0000x reference)
//
#include <hip/hip_runtime.h>

typedef unsigned short ushort_t;
typedef __attribute__((ext_vector_type(8))) short bf16x8;
typedef __attribute__((ext_vector_type(4))) float f32x4;

#define NN 50000
#define NE 600000
#define DD 128
#define LL 3
#define GG 512
#define NB_SCAN 98   // ceil(NN/512)
#define GGRID 782    // ceil(NN/64) gemm blocks (64 rows/block, round-14 geometry)
#define SBK 16       // stats banks

__device__ __forceinline__ float b2f(ushort_t u){ return __uint_as_float(((unsigned)u)<<16); }
__device__ __forceinline__ ushort_t f2b(float f){
    unsigned x = __float_as_uint(f);
    return (ushort_t)((x + 0x7fffu + ((x>>16)&1u)) >> 16);
}

// ---- marker for host-side input-layout mismatch (f32 out) ----
__global__ void k_mark(float* __restrict__ out, float val, int n){
    int i = blockIdx.x*256 + threadIdx.x; if (i >= n) return;
    out[i] = (i == 0) ? val : 0.f;
}

// ---- fused setup: wconv + goff + zero cnt + zero SR/banks/dcnt + layer-0 LUT ----
// [0,180224) wconv | +513 goff | +50000 cnt=0 | +34816 SR/banks=0 | +8 dcnt=0 | +768 lin0
struct WPtrs { const float* p[11]; };
__global__ void k_setup(WPtrs wp, ushort_t* __restrict__ Wf,
                        const int* __restrict__ bids, int* __restrict__ goff,
                        int* __restrict__ cnt, float* __restrict__ SRall,
                        int* __restrict__ dcnt,
                        const float* __restrict__ emb, const float* __restrict__ linW,
                        const float* __restrict__ linB, float* __restrict__ yrows){
    int idx = blockIdx.x*256 + threadIdx.x;
    if (idx < 180224){
        int m = idx >> 14, r = idx & 16383;
        int i = r & 7, l2 = (r >> 3) & 63, s = (r >> 9) & 3, n = r >> 11;
        int k   = s*32 + (l2 >> 4)*8 + i;
        int col = n*16 + (l2 & 15);
        Wf[idx] = f2b(wp.p[m][k*DD + col]);
    } else if (idx < 180737){
        int g = idx - 180224;            // 0..512
        int lo = 0, hi = NN;
        while (lo < hi){ int mid = (lo+hi) >> 1; if (bids[mid] < g) lo = mid+1; else hi = mid; }
        goff[g] = lo;
    } else if (idx < 230737){
        cnt[idx - 180737] = 0;
    } else if (idx < 265553){
        SRall[idx - 230737] = 0.f;       // 8*256 final + 8*SBK*256 banks
    } else if (idx < 265561){
        dcnt[idx - 265553] = 0;
    } else if (idx < 266329){
        int i = idx - 265561;            // 6*128
        int di = i >> 7, c = i & 127;
        float acc = linB[c];
        for (int k = 0; k < DD; k++) acc = fmaf(emb[di*DD + k], linW[k*DD + c], acc);
        yrows[i] = fmaxf(acc, 0.f);
    }
}

// ---------------- CSR: count (int4) ----------------
__global__ void k_count(const int* __restrict__ dst, int* __restrict__ cnt){
    int e4 = blockIdx.x*256 + threadIdx.x; if (e4 >= NE/4) return;
    int4 dv = ((const int4*)dst)[e4];
    atomicAdd(&cnt[dv.x], 1); atomicAdd(&cnt[dv.y], 1);
    atomicAdd(&cnt[dv.z], 1); atomicAdd(&cnt[dv.w], 1);
}
// ---------------- CSR: multi-block scan ----------------
__global__ void k_scanA(const int* __restrict__ cnt, int* __restrict__ inc, int* __restrict__ bsum){
    __shared__ int s[512];
    int i = blockIdx.x*512 + threadIdx.x;
    int v = (i < NN) ? cnt[i] : 0;
    s[threadIdx.x] = v; __syncthreads();
    for (int off = 1; off < 512; off <<= 1){
        int add = (threadIdx.x >= off) ? s[threadIdx.x - off] : 0;
        __syncthreads();
        s[threadIdx.x] += add;
        __syncthreads();
    }
    if (i < NN) inc[i] = s[threadIdx.x];
    if (threadIdx.x == 511) bsum[blockIdx.x] = s[511];
}
__global__ void k_scanB(const int* __restrict__ bsum, int* __restrict__ boff){
    __shared__ int s[128];
    int t = threadIdx.x;                  // 128
    int v = (t < NB_SCAN) ? bsum[t] : 0;
    s[t] = v; __syncthreads();
    for (int off = 1; off < 128; off <<= 1){
        int a = (t >= off) ? s[t - off] : 0;
        __syncthreads();
        s[t] += a;
        __syncthreads();
    }
    if (t < NB_SCAN) boff[t] = s[t] - v;
    if (t == NB_SCAN - 1) boff[NB_SCAN] = s[t];
}
__global__ void k_scanC(const int* __restrict__ cnt, const int* __restrict__ inc,
                        const int* __restrict__ boff, int* __restrict__ rowptr,
                        int* __restrict__ cursor){
    int i = blockIdx.x*512 + threadIdx.x;
    if (i < NN){
        int e = boff[blockIdx.x] + inc[i] - cnt[i];
        rowptr[i] = e; cursor[i] = e;
    } else if (i == NN){
        rowptr[NN] = NE;
    }
}
// ---------------- CSR: fill (int4 loads) ----------------
__global__ void k_fill(const int* __restrict__ src, const int* __restrict__ dst,
                       int* __restrict__ cursor, int* __restrict__ eidx){
    int e4 = blockIdx.x*256 + threadIdx.x; if (e4 >= NE/4) return;
    int4 dv = ((const int4*)dst)[e4];
    int4 sv = ((const int4*)src)[e4];
    int p0 = atomicAdd(&cursor[dv.x], 1); eidx[p0] = sv.x;
    int p1 = atomicAdd(&cursor[dv.y], 1); eidx[p1] = sv.y;
    int p2 = atomicAdd(&cursor[dv.z], 1); eidx[p2] = sv.z;
    int p3 = atomicAdd(&cursor[dv.w], 1); eidx[p3] = sv.w;
}

// ---- layer-0 aggregation from 6-row LUTs (all LDS) ----
__global__ void k_agg0(const int* __restrict__ d, const float* __restrict__ emb,
                       const float* __restrict__ yrows,
                       const int* __restrict__ rowptr, const int* __restrict__ eidx,
                       const float* __restrict__ epsP, ushort_t* __restrict__ zb){
    __shared__ float eL[6*DD], yL[6*DD];
    int t = threadIdx.x;
    for (int i = t; i < 6*DD; i += 256){ eL[i] = emb[i]; yL[i] = yrows[i]; }
    __syncthreads();
    int node = blockIdx.x*16 + (t >> 4);
    if (node >= NN) return;
    int c8 = (t & 15) << 3;
    float epl = 1.0f + epsP[0];
    int dv = d[node]; dv = dv < 0 ? 0 : (dv > 5 ? 5 : dv);
    float a[8];
#pragma unroll
    for (int i = 0; i < 8; i++) a[i] = eL[dv*DD + c8 + i] * epl;
    int e0 = rowptr[node], e1 = rowptr[node+1];
    int e = e0;
    for (; e + 3 < e1; e += 4){
        int s0 = eidx[e], s1 = eidx[e+1], s2 = eidx[e+2], s3 = eidx[e+3];
        int c0 = d[s0], c1 = d[s1], c2 = d[s2], c3 = d[s3];
        c0 = c0 < 0 ? 0 : (c0 > 5 ? 5 : c0);
        c1 = c1 < 0 ? 0 : (c1 > 5 ? 5 : c1);
        c2 = c2 < 0 ? 0 : (c2 > 5 ? 5 : c2);
        c3 = c3 < 0 ? 0 : (c3 > 5 ? 5 : c3);
#pragma unroll
        for (int i = 0; i < 8; i++)
            a[i] += (yL[c0*DD + c8 + i] + yL[c1*DD + c8 + i])
                  + (yL[c2*DD + c8 + i] + yL[c3*DD + c8 + i]);
    }
    for (; e < e1; e++){
        int s = eidx[e];
        int c = d[s]; c = c < 0 ? 0 : (c > 5 ? 5 : c);
#pragma unroll
        for (int i = 0; i < 8; i++) a[i] += yL[c*DD + c8 + i];
    }
    bf16x8 o;
#pragma unroll
    for (int i = 0; i < 8; i++) o[i] = (short)f2b(a[i]);
    *(bf16x8*)(zb + (size_t)node*DD + c8) = o;
}

// ---- aggregation layers>0 ----
__global__ void k_agg(const ushort_t* __restrict__ xb, const ushort_t* __restrict__ yb,
                      ushort_t* __restrict__ zb,
                      const int* __restrict__ rowptr, const int* __restrict__ eidx,
                      const float* __restrict__ epsP, int l,
                      const float* __restrict__ bnstats, const float* __restrict__ bng,
                      const float* __restrict__ bnb){
    int node = blockIdx.x*16 + (threadIdx.x >> 4);
    if (node >= NN) return;
    int c8 = (threadIdx.x & 15) << 3;
    float epl = 1.0f + epsP[l];
    bf16x8 xr = *(const bf16x8*)(xb + (size_t)node*DD + c8);
    float a[8];
#pragma unroll
    for (int i = 0; i < 8; i++){
        int c = c8 + i;
        float mu  = bnstats[c] * (1.0f/NN);
        float var = bnstats[c + DD] * (1.0f/NN) - mu*mu;
        float sc  = rsqrtf(fmaxf(var, 0.f) + 1e-5f) * bng[c];
        float sh  = bnb[c] - mu*sc;
        a[i] = fmaxf(fmaf(b2f((ushort_t)xr[i]), sc, sh), 0.f) * epl;
    }
    int e0 = rowptr[node], e1 = rowptr[node+1];
    int e = e0;
    for (; e + 3 < e1; e += 4){
        int s0 = eidx[e], s1 = eidx[e+1], s2 = eidx[e+2], s3 = eidx[e+3];
        bf16x8 v0 = *(const bf16x8*)(yb + (size_t)s0*DD + c8);
        bf16x8 v1 = *(const bf16x8*)(yb + (size_t)s1*DD + c8);
        bf16x8 v2 = *(const bf16x8*)(yb + (size_t)s2*DD + c8);
        bf16x8 v3 = *(const bf16x8*)(yb + (size_t)s3*DD + c8);
#pragma unroll
        for (int i = 0; i < 8; i++)
            a[i] += (b2f((ushort_t)v0[i]) + b2f((ushort_t)v1[i]))
                  + (b2f((ushort_t)v2[i]) + b2f((ushort_t)v3[i]));
    }
    for (; e < e1; e++){
        int s = eidx[e];
        bf16x8 v = *(const bf16x8*)(yb + (size_t)s*DD + c8);
#pragma unroll
        for (int i = 0; i < 8; i++) a[i] += b2f((ushort_t)v[i]);
    }
    bf16x8 o;
#pragma unroll
    for (int i = 0; i < 8; i++) o[i] = (short)f2b(a[i]);
    *(bf16x8*)(zb + (size_t)node*DD + c8) = o;
}

// ---------------- MFMA GEMM (round-14 64-row geometry) + banked stats ----------------
// AMODE 2: A'=relu(bn(A)).  OMODE 1: relu(C+bias).
// STATS: per-block column sum/sumsq -> bank atomics -> last-block reduce into stats_out.
// POOL: blocks >= GGRID do graph-pool of A (never run stats).
template<int AMODE, int OMODE, int STATS, int POOL>
__global__ __launch_bounds__(256) void k_gemm(
    const ushort_t* __restrict__ A, const ushort_t* __restrict__ Wf,
    const float* __restrict__ bias,
    const float* __restrict__ bnstats, const float* __restrict__ bng,
    const float* __restrict__ bnb,
    ushort_t* __restrict__ C, float* __restrict__ banks, int* __restrict__ dctr,
    float* __restrict__ stats_out,
    const int* __restrict__ goff, float* __restrict__ pool_out, int M)
{
    __shared__ float ssl[256];
    __shared__ float sred[256];
    __shared__ float lrep[64*132];
    const int t = threadIdx.x;

    if (POOL && blockIdx.x >= GGRID){
        int g = blockIdx.x - GGRID;
        int c = t & 127, hf = t >> 7;
        float mu  = bnstats[c] * (1.0f/NN);
        float var = bnstats[c + DD] * (1.0f/NN) - mu*mu;
        float sc  = rsqrtf(fmaxf(var, 0.f) + 1e-5f) * bng[c];
        float sh  = bnb[c] - mu*sc;
        int r0 = goff[g], r1 = goff[g+1];
        float acc = 0.f;
        for (int r = r0 + hf; r < r1; r += 2)
            acc += fmaxf(fmaf(b2f(A[(size_t)r*DD + c]), sc, sh), 0.f);
        sred[t] = acc; __syncthreads();
        if (t < 128)
            pool_out[g*DD + t] = (sred[t] + sred[t+128]) / fmaxf((float)(r1 - r0), 1.0f);
        return;
    }

    const int w = t >> 6, l = t & 63;
    const int rowBlk = blockIdx.x*64, rowBase = rowBlk + w*16;
    const int lm = l & 15, kg = l >> 4;

    if (AMODE == 2 && t < 128){
        float mu  = bnstats[t] * (1.0f/NN);
        float var = bnstats[t + DD] * (1.0f/NN) - mu*mu;
        float sc  = rsqrtf(fmaxf(var, 0.f) + 1e-5f) * bng[t];
        ssl[t] = sc;
        ssl[t + DD] = bnb[t] - mu*sc;
    }
    if (STATS) sred[t] = 0.f;
    if (AMODE == 2 || STATS) __syncthreads();

    f32x4 acc[8];
#pragma unroll
    for (int n = 0; n < 8; n++) acc[n] = (f32x4){0.f,0.f,0.f,0.f};

    int arow = rowBase + lm;
    if (arow >= M) arow = M - 1;
    const ushort_t* aptr = A + (size_t)arow*DD + kg*8;

#pragma unroll
    for (int s = 0; s < 4; s++){
        bf16x8 af;
        if (AMODE == 0){
            af = *(const bf16x8*)(aptr + s*32);
        } else {
            bf16x8 ar = *(const bf16x8*)(aptr + s*32);
            int k0 = s*32 + kg*8;
#pragma unroll
            for (int i = 0; i < 8; i++){
                float v = b2f((ushort_t)ar[i]);
                v = fmaxf(fmaf(v, ssl[k0+i], ssl[DD+k0+i]), 0.f);
                ((ushort_t*)&af)[i] = f2b(v);
            }
        }
#pragma unroll
        for (int n = 0; n < 8; n++){
            bf16x8 bfr = *(const bf16x8*)(Wf + (size_t)((n*4 + s)*64 + l)*8);
            acc[n] = __builtin_amdgcn_mfma_f32_16x16x32_bf16(af, bfr, acc[n], 0, 0, 0);
        }
    }

#pragma unroll
    for (int n = 0; n < 8; n++){
        int col = n*16 + lm;
        float cs = 0.f, cq = 0.f;
#pragma unroll
        for (int j = 0; j < 4; j++){
            float v = acc[n][j];
            if (OMODE == 1) v = fmaxf(v + bias[col], 0.f);
            lrep[(w*16 + kg*4 + j)*132 + col] = v;
            if (STATS && (rowBase + kg*4 + j) < M){ cs += v; cq += v*v; }
        }
        if (STATS){
            cs += __shfl_xor(cs, 16); cs += __shfl_xor(cs, 32);
            cq += __shfl_xor(cq, 16); cq += __shfl_xor(cq, 32);
            if (kg == 0){
                atomicAdd(&sred[col], cs);
                atomicAdd(&sred[col + DD], cq);
            }
        }
    }
    __syncthreads();

    {
        int lr = t & 63;
        int gr = rowBlk + lr;
        if (gr < M){
            int seg = (t >> 6) * 32;
            const float* lp = lrep + lr*132 + seg;
            bf16x8 o0, o1, o2, o3;
#pragma unroll
            for (int i = 0; i < 8; i++){
                o0[i] = (short)f2b(lp[i]);
                o1[i] = (short)f2b(lp[8+i]);
                o2[i] = (short)f2b(lp[16+i]);
                o3[i] = (short)f2b(lp[24+i]);
            }
            ushort_t* cp = C + (size_t)gr*DD + seg;
            *(bf16x8*)(cp)      = o0;
            *(bf16x8*)(cp + 8)  = o1;
            *(bf16x8*)(cp + 16) = o2;
            *(bf16x8*)(cp + 24) = o3;
        }
    }

    if (STATS){
        __syncthreads();
        // banked atomic (depth ~49 per address instead of 782)
        atomicAdd(&banks[((blockIdx.x & (SBK-1)) << 8) + t], sred[t]);
        __threadfence();
        __shared__ int lastB;
        if (t == 0) lastB = (atomicAdd(dctr, 1) == GGRID - 1) ? 1 : 0;
        __syncthreads();
        if (lastB){
            // coherent bank reads via atomic-add-zero (cross-XCD safe), then final store
            float s = 0.f;
#pragma unroll
            for (int b = 0; b < SBK; b++)
                s += atomicAdd(&banks[(b << 8) + t], 0.0f);
            stats_out[t] = s;
        }
    }
}

// ---------------- fused h_graph pool + predict head: block g -> out ----------------
__global__ __launch_bounds__(256) void k_poolpred(const ushort_t* __restrict__ zb,
        const float* __restrict__ bnstats, const float* __restrict__ bng,
        const float* __restrict__ bnb, const int* __restrict__ goff,
        const float* __restrict__ W1, const float* __restrict__ b1,
        const float* __restrict__ W2, const float* __restrict__ b2,
        float* __restrict__ out_hgraph, float* __restrict__ out_pred){
    __shared__ float hrow[DD];
    __shared__ float pr[256];
    int g = blockIdx.x, t = threadIdx.x;
    int c = t & 127, hf = t >> 7;
    float mu  = bnstats[c] * (1.0f/NN);
    float var = bnstats[c + DD] * (1.0f/NN) - mu*mu;
    float sc  = rsqrtf(fmaxf(var, 0.f) + 1e-5f) * bng[c];
    float sh  = bnb[c] - mu*sc;
    int r0 = goff[g], r1 = goff[g+1];
    float acc = 0.f;
    for (int r = r0 + hf; r < r1; r += 2)
        acc += fmaxf(fmaf(b2f(zb[(size_t)r*DD + c]), sc, sh), 0.f);
    pr[t] = acc; __syncthreads();
    if (t < 128){
        float m = (pr[t] + pr[t+128]) / fmaxf((float)(r1 - r0), 1.0f);
        hrow[t] = m;
        out_hgraph[g*DD + t] = m;
    }
    __syncthreads();
    float a2 = b1[t];
    for (int k = 0; k < DD; k++) a2 = fmaf(hrow[k], W1[k*256 + t], a2);
    pr[t] = fmaxf(a2, 0.f) * W2[t];
    __syncthreads();
    for (int off = 128; off > 0; off >>= 1){
        if (t < off) pr[t] += pr[t + off];
        __syncthreads();
    }
    if (t == 0) out_pred[g] = pr[0] + b2[0];
}

extern "C" void kernel_launch(void* const* d_in, const int* in_sizes, int n_in,
                              void* d_out, int out_size, void* d_ws, size_t ws_size,
                              hipStream_t stream){
    float* out = (float*)d_out;
    const int OUT_N = GG + GG*DD + LL*GG*DD;      // 262656

    static const int EXP[24] = {50000,600000,600000,50000, 768,49152,384,49152,384,384,
                                49152,3,384,384,16384,128,128,16384,128,128,
                                32768,256,256,1};
    int bad = -1;
    if (n_in != 24) bad = 50;
    else for (int i = 0; i < 24; i++) if (in_sizes[i] != EXP[i]) { bad = i; break; }
    if (bad >= 0){
        k_mark<<<(OUT_N+255)/256, 256, 0, stream>>>(out, 2048.0f + (float)bad, OUT_N);
        return;
    }

    const int* d    = (const int*)d_in[0];
    const int* src  = (const int*)d_in[1];
    const int* dst  = (const int*)d_in[2];
    const int* bids = (const int*)d_in[3];
    const float* emb  = (const float*)d_in[4];
    const float* linW = (const float*)d_in[5];
    const float* linB = (const float*)d_in[6];
    const float* W1   = (const float*)d_in[7];
    const float* g1   = (const float*)d_in[8];
    const float* b1   = (const float*)d_in[9];
    const float* W2   = (const float*)d_in[10];
    const float* epsA = (const float*)d_in[11];
    const float* bng  = (const float*)d_in[12];
    const float* bnb  = (const float*)d_in[13];
    const float* pW1  = (const float*)d_in[14];
    const float* pg1  = (const float*)d_in[15];
    const float* pb1  = (const float*)d_in[16];
    const float* pW2  = (const float*)d_in[17];
    const float* pbng = (const float*)d_in[18];
    const float* pbnb = (const float*)d_in[19];
    const float* prW1 = (const float*)d_in[20];
    const float* prb1 = (const float*)d_in[21];
    const float* prW2 = (const float*)d_in[22];
    const float* prb2 = (const float*)d_in[23];

    // ---- workspace (~45 MB) ----
    ushort_t* xb  = (ushort_t*)d_ws;
    ushort_t* yb  = xb + (size_t)NN*DD;
    ushort_t* zb  = yb + (size_t)NN*DD;
    ushort_t* Wf  = zb + (size_t)NN*DD;           // 11*16384 bf16
    float* SR    = (float*)(Wf + 11*16384);       // 8*256 final stats
    float* SBANKS= SR + 8*256;                    // 8*SBK*256 bank stats
    float* yrows = SBANKS + 8*SBK*256;            // 6*128
    int* DCNT   = (int*)(yrows + 6*DD);           // 8
    int* cnt    = DCNT + 8;
    int* inc    = cnt + NN;
    int* rowptr = inc + NN;                       // N+1
    int* cursor = rowptr + NN + 1;
    int* eidx   = cursor + NN;                    // E
    int* goff   = eidx + NE;                      // G+1
    int* bsum   = goff + GG + 1;
    int* boff   = bsum + NB_SCAN;

    float* out_pred   = out;
    float* out_hgraph = out + GG;
    float* out_hmeans = out + GG + GG*DD;

    const int AGG_GRID  = (NN + 15)/16;           // 3125
    const int E4_GRID   = (NE/4 + 255)/256;       // 586
    const int SETUP_GRID= (266329 + 255)/256;     // 1041
    const int GP_GRID   = GGRID + GG;             // 1294 (gemm + fused pool)

    WPtrs wp;
    for (int i = 0; i < 3; i++){
        wp.p[i]   = linW + (size_t)i*DD*DD;
        wp.p[3+i] = W1   + (size_t)i*DD*DD;
        wp.p[6+i] = W2   + (size_t)i*DD*DD;
    }
    wp.p[9] = pW1; wp.p[10] = pW2;
    const ushort_t* WfLin = Wf;
    const ushort_t* WfW1  = Wf + 3*16384;
    const ushort_t* WfW2  = Wf + 6*16384;
    const ushort_t* WfPW1 = Wf + 9*16384;
    const ushort_t* WfPW2 = Wf + 10*16384;

    // setup + CSR
    k_setup<<<SETUP_GRID, 256, 0, stream>>>(wp, Wf, bids, goff, cnt, SR, DCNT,
                                            emb, linW, linB, yrows);
    k_count<<<E4_GRID, 256, 0, stream>>>(dst, cnt);
    k_scanA<<<NB_SCAN, 512, 0, stream>>>(cnt, inc, bsum);
    k_scanB<<<1, 128, 0, stream>>>(bsum, boff);
    k_scanC<<<NB_SCAN, 512, 0, stream>>>(cnt, inc, boff, rowptr, cursor);
    k_fill<<<E4_GRID, 256, 0, stream>>>(src, dst, cursor, eidx);

    // ---- layer 0 ----
    k_agg0<<<AGG_GRID, 256, 0, stream>>>(d, emb, yrows, rowptr, eidx, epsA, zb);
    k_gemm<0,0,1,0><<<GGRID, 256, 0, stream>>>(zb, WfW1, nullptr, nullptr, nullptr, nullptr,
        yb, SBANKS + 0*SBK*256, DCNT + 0, SR + 0*256, nullptr, nullptr, NN);
    k_gemm<2,0,1,0><<<GGRID, 256, 0, stream>>>(yb, WfW2, nullptr, SR + 0*256, g1, b1,
        xb, SBANKS + 1*SBK*256, DCNT + 1, SR + 1*256, nullptr, nullptr, NN);

    // ---- layers 1,2 (lin-GEMM carries previous layer's h_means pool) ----
    for (int l = 1; l < LL; l++){
        const float* pstat = SR + (2*l - 1)*256;
        const float* pg    = bng + (size_t)(l-1)*DD;
        const float* pb    = bnb + (size_t)(l-1)*DD;
        int iIn  = 2*l;
        int iOut = 2*l + 1;

        k_gemm<2,1,0,1><<<GP_GRID, 256, 0, stream>>>(xb, WfLin + (size_t)l*16384,
            linB + (size_t)l*DD, pstat, pg, pb,
            yb, nullptr, nullptr, nullptr, goff, out_hmeans + (size_t)(l-1)*GG*DD, NN);
        k_agg<<<AGG_GRID, 256, 0, stream>>>(xb, yb, zb, rowptr, eidx, epsA, l, pstat, pg, pb);
        k_gemm<0,0,1,0><<<GGRID, 256, 0, stream>>>(zb, WfW1 + (size_t)l*16384, nullptr,
            nullptr, nullptr, nullptr, yb, SBANKS + (size_t)iIn*SBK*256, DCNT + iIn,
            SR + (size_t)iIn*256, nullptr, nullptr, NN);
        k_gemm<2,0,1,0><<<GGRID, 256, 0, stream>>>(yb, WfW2 + (size_t)l*16384, nullptr,
            SR + (size_t)iIn*256, g1 + (size_t)l*DD, b1 + (size_t)l*DD,
            xb, SBANKS + (size_t)iOut*SBK*256, DCNT + iOut, SR + (size_t)iOut*256,
            nullptr, nullptr, NN);
    }

    // ---- pooling MLP (pW1-GEMM carries layer-2 h_means pool) ----
    k_gemm<2,0,1,1><<<GP_GRID, 256, 0, stream>>>(xb, WfPW1, nullptr,
        SR + 5*256, bng + 2*DD, bnb + 2*DD,
        yb, SBANKS + 6*SBK*256, DCNT + 6, SR + 6*256,
        goff, out_hmeans + (size_t)2*GG*DD, NN);
    k_gemm<2,0,1,0><<<GGRID, 256, 0, stream>>>(yb, WfPW2, nullptr,
        SR + 6*256, pg1, pb1, zb, SBANKS + 7*SBK*256, DCNT + 7, SR + 7*256,
        nullptr, nullptr, NN);
    // h_graph pool + predict (fused)
    k_poolpred<<<GG, 256, 0, stream>>>(zb, SR + 7*256, pbng, pbnb, goff,
        prW1, prb1, prW2, prb2, out_hgraph, out_pred);
}

// Round 17
// 387.804 us; speedup vs baseline: 3.1020x; 3.1020x over previous
//
#include <hip/hip_runtime.h>

typedef unsigned short ushort_t;
typedef __attribute__((ext_vector_type(8))) short bf16x8;
typedef __attribute__((ext_vector_type(4))) float f32x4;

#define NN 50000
#define NE 600000
#define DD 128
#define LL 3
#define GG 512
#define NB_SCAN 98   // ceil(NN/512)
#define GGRID 782    // ceil(NN/64) gemm blocks (64 rows/block)
#define SBK 16       // stats banks (line-separated; atomic depth 782 -> ~49)

__device__ __forceinline__ float b2f(ushort_t u){ return __uint_as_float(((unsigned)u)<<16); }
__device__ __forceinline__ ushort_t f2b(float f){
    unsigned x = __float_as_uint(f);
    return (ushort_t)((x + 0x7fffu + ((x>>16)&1u)) >> 16);
}

// ---- marker for host-side input-layout mismatch (f32 out) ----
__global__ void k_mark(float* __restrict__ out, float val, int n){
    int i = blockIdx.x*256 + threadIdx.x; if (i >= n) return;
    out[i] = (i == 0) ? val : 0.f;
}

// ---- fused setup: wconv + goff + zero cnt + zero banks + layer-0 LUT ----
// [0,180224) wconv | +513 goff | +50000 cnt=0 | +32768 banks=0 | +768 lin0
struct WPtrs { const float* p[11]; };
__global__ void k_setup(WPtrs wp, ushort_t* __restrict__ Wf,
                        const int* __restrict__ bids, int* __restrict__ goff,
                        int* __restrict__ cnt, float* __restrict__ banks,
                        const float* __restrict__ emb, const float* __restrict__ linW,
                        const float* __restrict__ linB, float* __restrict__ yrows){
    int idx = blockIdx.x*256 + threadIdx.x;
    if (idx < 180224){
        int m = idx >> 14, r = idx & 16383;
        int i = r & 7, l2 = (r >> 3) & 63, s = (r >> 9) & 3, n = r >> 11;
        int k   = s*32 + (l2 >> 4)*8 + i;
        int col = n*16 + (l2 & 15);
        Wf[idx] = f2b(wp.p[m][k*DD + col]);
    } else if (idx < 180737){
        int g = idx - 180224;            // 0..512
        int lo = 0, hi = NN;
        while (lo < hi){ int mid = (lo+hi) >> 1; if (bids[mid] < g) lo = mid+1; else hi = mid; }
        goff[g] = lo;
    } else if (idx < 230737){
        cnt[idx - 180737] = 0;
    } else if (idx < 263505){
        banks[idx - 230737] = 0.f;       // 8 instances * SBK * 256
    } else if (idx < 264273){
        int i = idx - 263505;            // 6*128
        int di = i >> 7, c = i & 127;
        float acc = linB[c];
        for (int k = 0; k < DD; k++) acc = fmaf(emb[di*DD + k], linW[k*DD + c], acc);
        yrows[i] = fmaxf(acc, 0.f);
    }
}

// ---------------- CSR: count (int4) ----------------
__global__ void k_count(const int* __restrict__ dst, int* __restrict__ cnt){
    int e4 = blockIdx.x*256 + threadIdx.x; if (e4 >= NE/4) return;
    int4 dv = ((const int4*)dst)[e4];
    atomicAdd(&cnt[dv.x], 1); atomicAdd(&cnt[dv.y], 1);
    atomicAdd(&cnt[dv.z], 1); atomicAdd(&cnt[dv.w], 1);
}
// ---------------- CSR: multi-block scan ----------------
__global__ void k_scanA(const int* __restrict__ cnt, int* __restrict__ inc, int* __restrict__ bsum){
    __shared__ int s[512];
    int i = blockIdx.x*512 + threadIdx.x;
    int v = (i < NN) ? cnt[i] : 0;
    s[threadIdx.x] = v; __syncthreads();
    for (int off = 1; off < 512; off <<= 1){
        int add = (threadIdx.x >= off) ? s[threadIdx.x - off] : 0;
        __syncthreads();
        s[threadIdx.x] += add;
        __syncthreads();
    }
    if (i < NN) inc[i] = s[threadIdx.x];
    if (threadIdx.x == 511) bsum[blockIdx.x] = s[511];
}
__global__ void k_scanB(const int* __restrict__ bsum, int* __restrict__ boff){
    __shared__ int s[128];
    int t = threadIdx.x;                  // 128
    int v = (t < NB_SCAN) ? bsum[t] : 0;
    s[t] = v; __syncthreads();
    for (int off = 1; off < 128; off <<= 1){
        int a = (t >= off) ? s[t - off] : 0;
        __syncthreads();
        s[t] += a;
        __syncthreads();
    }
    if (t < NB_SCAN) boff[t] = s[t] - v;
    if (t == NB_SCAN - 1) boff[NB_SCAN] = s[t];
}
__global__ void k_scanC(const int* __restrict__ cnt, const int* __restrict__ inc,
                        const int* __restrict__ boff, int* __restrict__ rowptr,
                        int* __restrict__ cursor){
    int i = blockIdx.x*512 + threadIdx.x;
    if (i < NN){
        int e = boff[blockIdx.x] + inc[i] - cnt[i];
        rowptr[i] = e; cursor[i] = e;
    } else if (i == NN){
        rowptr[NN] = NE;
    }
}
// ---------------- CSR: fill (int4 loads) ----------------
__global__ void k_fill(const int* __restrict__ src, const int* __restrict__ dst,
                       int* __restrict__ cursor, int* __restrict__ eidx){
    int e4 = blockIdx.x*256 + threadIdx.x; if (e4 >= NE/4) return;
    int4 dv = ((const int4*)dst)[e4];
    int4 sv = ((const int4*)src)[e4];
    int p0 = atomicAdd(&cursor[dv.x], 1); eidx[p0] = sv.x;
    int p1 = atomicAdd(&cursor[dv.y], 1); eidx[p1] = sv.y;
    int p2 = atomicAdd(&cursor[dv.z], 1); eidx[p2] = sv.z;
    int p3 = atomicAdd(&cursor[dv.w], 1); eidx[p3] = sv.w;
}

// ---- layer-0 aggregation from 6-row LUTs (all LDS) ----
__global__ void k_agg0(const int* __restrict__ d, const float* __restrict__ emb,
                       const float* __restrict__ yrows,
                       const int* __restrict__ rowptr, const int* __restrict__ eidx,
                       const float* __restrict__ epsP, ushort_t* __restrict__ zb){
    __shared__ float eL[6*DD], yL[6*DD];
    int t = threadIdx.x;
    for (int i = t; i < 6*DD; i += 256){ eL[i] = emb[i]; yL[i] = yrows[i]; }
    __syncthreads();
    int node = blockIdx.x*16 + (t >> 4);
    if (node >= NN) return;
    int c8 = (t & 15) << 3;
    float epl = 1.0f + epsP[0];
    int dv = d[node]; dv = dv < 0 ? 0 : (dv > 5 ? 5 : dv);
    float a[8];
#pragma unroll
    for (int i = 0; i < 8; i++) a[i] = eL[dv*DD + c8 + i] * epl;
    int e0 = rowptr[node], e1 = rowptr[node+1];
    int e = e0;
    for (; e + 3 < e1; e += 4){
        int s0 = eidx[e], s1 = eidx[e+1], s2 = eidx[e+2], s3 = eidx[e+3];
        int c0 = d[s0], c1 = d[s1], c2 = d[s2], c3 = d[s3];
        c0 = c0 < 0 ? 0 : (c0 > 5 ? 5 : c0);
        c1 = c1 < 0 ? 0 : (c1 > 5 ? 5 : c1);
        c2 = c2 < 0 ? 0 : (c2 > 5 ? 5 : c2);
        c3 = c3 < 0 ? 0 : (c3 > 5 ? 5 : c3);
#pragma unroll
        for (int i = 0; i < 8; i++)
            a[i] += (yL[c0*DD + c8 + i] + yL[c1*DD + c8 + i])
                  + (yL[c2*DD + c8 + i] + yL[c3*DD + c8 + i]);
    }
    for (; e < e1; e++){
        int s = eidx[e];
        int c = d[s]; c = c < 0 ? 0 : (c > 5 ? 5 : c);
#pragma unroll
        for (int i = 0; i < 8; i++) a[i] += yL[c*DD + c8 + i];
    }
    bf16x8 o;
#pragma unroll
    for (int i = 0; i < 8; i++) o[i] = (short)f2b(a[i]);
    *(bf16x8*)(zb + (size_t)node*DD + c8) = o;
}

// ---- aggregation layers>0: BN scale/shift from 16-bank stats (summed in LDS) ----
__global__ void k_agg(const ushort_t* __restrict__ xb, const ushort_t* __restrict__ yb,
                      ushort_t* __restrict__ zb,
                      const int* __restrict__ rowptr, const int* __restrict__ eidx,
                      const float* __restrict__ epsP, int l,
                      const float* __restrict__ banksIn, const float* __restrict__ bng,
                      const float* __restrict__ bnb){
    __shared__ float sst[256];
    int t = threadIdx.x;
    {
        float sv = 0.f;
#pragma unroll
        for (int b = 0; b < SBK; b++) sv += banksIn[(b << 8) + t];
        sst[t] = sv;
    }
    __syncthreads();
    int node = blockIdx.x*16 + (t >> 4);
    if (node >= NN) return;
    int c8 = (t & 15) << 3;
    float epl = 1.0f + epsP[l];
    bf16x8 xr = *(const bf16x8*)(xb + (size_t)node*DD + c8);
    float a[8];
#pragma unroll
    for (int i = 0; i < 8; i++){
        int c = c8 + i;
        float mu  = sst[c] * (1.0f/NN);
        float var = sst[c + DD] * (1.0f/NN) - mu*mu;
        float sc  = rsqrtf(fmaxf(var, 0.f) + 1e-5f) * bng[c];
        float sh  = bnb[c] - mu*sc;
        a[i] = fmaxf(fmaf(b2f((ushort_t)xr[i]), sc, sh), 0.f) * epl;
    }
    int e0 = rowptr[node], e1 = rowptr[node+1];
    int e = e0;
    for (; e + 3 < e1; e += 4){
        int s0 = eidx[e], s1 = eidx[e+1], s2 = eidx[e+2], s3 = eidx[e+3];
        bf16x8 v0 = *(const bf16x8*)(yb + (size_t)s0*DD + c8);
        bf16x8 v1 = *(const bf16x8*)(yb + (size_t)s1*DD + c8);
        bf16x8 v2 = *(const bf16x8*)(yb + (size_t)s2*DD + c8);
        bf16x8 v3 = *(const bf16x8*)(yb + (size_t)s3*DD + c8);
#pragma unroll
        for (int i = 0; i < 8; i++)
            a[i] += (b2f((ushort_t)v0[i]) + b2f((ushort_t)v1[i]))
                  + (b2f((ushort_t)v2[i]) + b2f((ushort_t)v3[i]));
    }
    for (; e < e1; e++){
        int s = eidx[e];
        bf16x8 v = *(const bf16x8*)(yb + (size_t)s*DD + c8);
#pragma unroll
        for (int i = 0; i < 8; i++) a[i] += b2f((ushort_t)v[i]);
    }
    bf16x8 o;
#pragma unroll
    for (int i = 0; i < 8; i++) o[i] = (short)f2b(a[i]);
    *(bf16x8*)(zb + (size_t)node*DD + c8) = o;
}

// ---------------- MFMA GEMM (round-14 geometry) + banked stats, no fences ----------------
// AMODE 2: A'=relu(bn(A)), scale/shift from 16-bank sum.  OMODE 1: relu(C+bias).
// STATS: per-block column sum/sumsq -> one bank atomic per thread (bank = blockIdx&15).
// POOL: blocks >= GGRID do graph-pool of A using the same banked stats.
template<int AMODE, int OMODE, int STATS, int POOL>
__global__ __launch_bounds__(256) void k_gemm(
    const ushort_t* __restrict__ A, const ushort_t* __restrict__ Wf,
    const float* __restrict__ bias,
    const float* __restrict__ banksIn, const float* __restrict__ bng,
    const float* __restrict__ bnb,
    ushort_t* __restrict__ C, float* __restrict__ banksOut,
    const int* __restrict__ goff, float* __restrict__ pool_out, int M)
{
    __shared__ float ssl[256];
    __shared__ float sred[256];
    __shared__ float lrep[64*132];
    const int t = threadIdx.x;

    if (POOL && blockIdx.x >= GGRID){
        int g = blockIdx.x - GGRID;
        {
            float sv = 0.f;
#pragma unroll
            for (int b = 0; b < SBK; b++) sv += banksIn[(b << 8) + t];
            ssl[t] = sv;
        }
        __syncthreads();
        int c = t & 127, hf = t >> 7;
        float mu  = ssl[c] * (1.0f/NN);
        float var = ssl[c + DD] * (1.0f/NN) - mu*mu;
        float sc  = rsqrtf(fmaxf(var, 0.f) + 1e-5f) * bng[c];
        float sh  = bnb[c] - mu*sc;
        int r0 = goff[g], r1 = goff[g+1];
        float acc = 0.f;
        for (int r = r0 + hf; r < r1; r += 2)
            acc += fmaxf(fmaf(b2f(A[(size_t)r*DD + c]), sc, sh), 0.f);
        sred[t] = acc; __syncthreads();
        if (t < 128)
            pool_out[g*DD + t] = (sred[t] + sred[t+128]) / fmaxf((float)(r1 - r0), 1.0f);
        return;
    }

    const int w = t >> 6, l = t & 63;
    const int rowBlk = blockIdx.x*64, rowBase = rowBlk + w*16;
    const int lm = l & 15, kg = l >> 4;

    if (AMODE == 2){
        float sv = 0.f;
#pragma unroll
        for (int b = 0; b < SBK; b++) sv += banksIn[(b << 8) + t];
        ssl[t] = sv;
        __syncthreads();
        if (t < 128){
            float mu  = ssl[t] * (1.0f/NN);
            float var = ssl[t + DD] * (1.0f/NN) - mu*mu;
            float sc  = rsqrtf(fmaxf(var, 0.f) + 1e-5f) * bng[t];
            ssl[t] = sc;
            ssl[t + DD] = bnb[t] - mu*sc;
        }
    }
    if (STATS) sred[t] = 0.f;
    if (AMODE == 2 || STATS) __syncthreads();

    f32x4 acc[8];
#pragma unroll
    for (int n = 0; n < 8; n++) acc[n] = (f32x4){0.f,0.f,0.f,0.f};

    int arow = rowBase + lm;
    if (arow >= M) arow = M - 1;
    const ushort_t* aptr = A + (size_t)arow*DD + kg*8;

#pragma unroll
    for (int s = 0; s < 4; s++){
        bf16x8 af;
        if (AMODE == 0){
            af = *(const bf16x8*)(aptr + s*32);
        } else {
            bf16x8 ar = *(const bf16x8*)(aptr + s*32);
            int k0 = s*32 + kg*8;
#pragma unroll
            for (int i = 0; i < 8; i++){
                float v = b2f((ushort_t)ar[i]);
                v = fmaxf(fmaf(v, ssl[k0+i], ssl[DD+k0+i]), 0.f);
                ((ushort_t*)&af)[i] = f2b(v);
            }
        }
#pragma unroll
        for (int n = 0; n < 8; n++){
            bf16x8 bfr = *(const bf16x8*)(Wf + (size_t)((n*4 + s)*64 + l)*8);
            acc[n] = __builtin_amdgcn_mfma_f32_16x16x32_bf16(af, bfr, acc[n], 0, 0, 0);
        }
    }

#pragma unroll
    for (int n = 0; n < 8; n++){
        int col = n*16 + lm;
        float cs = 0.f, cq = 0.f;
#pragma unroll
        for (int j = 0; j < 4; j++){
            float v = acc[n][j];
            if (OMODE == 1) v = fmaxf(v + bias[col], 0.f);
            lrep[(w*16 + kg*4 + j)*132 + col] = v;
            if (STATS && (rowBase + kg*4 + j) < M){ cs += v; cq += v*v; }
        }
        if (STATS){
            cs += __shfl_xor(cs, 16); cs += __shfl_xor(cs, 32);
            cq += __shfl_xor(cq, 16); cq += __shfl_xor(cq, 32);
            if (kg == 0){
                atomicAdd(&sred[col], cs);
                atomicAdd(&sred[col + DD], cq);
            }
        }
    }
    __syncthreads();

    {
        int lr = t & 63;
        int gr = rowBlk + lr;
        if (gr < M){
            int seg = (t >> 6) * 32;
            const float* lp = lrep + lr*132 + seg;
            bf16x8 o0, o1, o2, o3;
#pragma unroll
            for (int i = 0; i < 8; i++){
                o0[i] = (short)f2b(lp[i]);
                o1[i] = (short)f2b(lp[8+i]);
                o2[i] = (short)f2b(lp[16+i]);
                o3[i] = (short)f2b(lp[24+i]);
            }
            ushort_t* cp = C + (size_t)gr*DD + seg;
            *(bf16x8*)(cp)      = o0;
            *(bf16x8*)(cp + 8)  = o1;
            *(bf16x8*)(cp + 16) = o2;
            *(bf16x8*)(cp + 24) = o3;
        }
    }

    if (STATS){
        __syncthreads();
        atomicAdd(&banksOut[((blockIdx.x & (SBK-1)) << 8) + t], sred[t]);
    }
}

// ---------------- fused h_graph pool + predict head (banked stats in) ----------------
__global__ __launch_bounds__(256) void k_poolpred(const ushort_t* __restrict__ zb,
        const float* __restrict__ banksIn, const float* __restrict__ bng,
        const float* __restrict__ bnb, const int* __restrict__ goff,
        const float* __restrict__ W1, const float* __restrict__ b1,
        const float* __restrict__ W2, const float* __restrict__ b2,
        float* __restrict__ out_hgraph, float* __restrict__ out_pred){
    __shared__ float hrow[DD];
    __shared__ float pr[256];
    int g = blockIdx.x, t = threadIdx.x;
    {
        float sv = 0.f;
#pragma unroll
        for (int b = 0; b < SBK; b++) sv += banksIn[(b << 8) + t];
        pr[t] = sv;
    }
    __syncthreads();
    int c = t & 127, hf = t >> 7;
    float mu  = pr[c] * (1.0f/NN);
    float var = pr[c + DD] * (1.0f/NN) - mu*mu;
    float sc  = rsqrtf(fmaxf(var, 0.f) + 1e-5f) * bng[c];
    float sh  = bnb[c] - mu*sc;
    __syncthreads();
    int r0 = goff[g], r1 = goff[g+1];
    float acc = 0.f;
    for (int r = r0 + hf; r < r1; r += 2)
        acc += fmaxf(fmaf(b2f(zb[(size_t)r*DD + c]), sc, sh), 0.f);
    pr[t] = acc; __syncthreads();
    if (t < 128){
        float m = (pr[t] + pr[t+128]) / fmaxf((float)(r1 - r0), 1.0f);
        hrow[t] = m;
        out_hgraph[g*DD + t] = m;
    }
    __syncthreads();
    float a2 = b1[t];
    for (int k = 0; k < DD; k++) a2 = fmaf(hrow[k], W1[k*256 + t], a2);
    pr[t] = fmaxf(a2, 0.f) * W2[t];
    __syncthreads();
    for (int off = 128; off > 0; off >>= 1){
        if (t < off) pr[t] += pr[t + off];
        __syncthreads();
    }
    if (t == 0) out_pred[g] = pr[0] + b2[0];
}

extern "C" void kernel_launch(void* const* d_in, const int* in_sizes, int n_in,
                              void* d_out, int out_size, void* d_ws, size_t ws_size,
                              hipStream_t stream){
    float* out = (float*)d_out;
    const int OUT_N = GG + GG*DD + LL*GG*DD;      // 262656

    static const int EXP[24] = {50000,600000,600000,50000, 768,49152,384,49152,384,384,
                                49152,3,384,384,16384,128,128,16384,128,128,
                                32768,256,256,1};
    int bad = -1;
    if (n_in != 24) bad = 50;
    else for (int i = 0; i < 24; i++) if (in_sizes[i] != EXP[i]) { bad = i; break; }
    if (bad >= 0){
        k_mark<<<(OUT_N+255)/256, 256, 0, stream>>>(out, 2048.0f + (float)bad, OUT_N);
        return;
    }

    const int* d    = (const int*)d_in[0];
    const int* src  = (const int*)d_in[1];
    const int* dst  = (const int*)d_in[2];
    const int* bids = (const int*)d_in[3];
    const float* emb  = (const float*)d_in[4];
    const float* linW = (const float*)d_in[5];
    const float* linB = (const float*)d_in[6];
    const float* W1   = (const float*)d_in[7];
    const float* g1   = (const float*)d_in[8];
    const float* b1   = (const float*)d_in[9];
    const float* W2   = (const float*)d_in[10];
    const float* epsA = (const float*)d_in[11];
    const float* bng  = (const float*)d_in[12];
    const float* bnb  = (const float*)d_in[13];
    const float* pW1  = (const float*)d_in[14];
    const float* pg1  = (const float*)d_in[15];
    const float* pb1  = (const float*)d_in[16];
    const float* pW2  = (const float*)d_in[17];
    const float* pbng = (const float*)d_in[18];
    const float* pbnb = (const float*)d_in[19];
    const float* prW1 = (const float*)d_in[20];
    const float* prb1 = (const float*)d_in[21];
    const float* prW2 = (const float*)d_in[22];
    const float* prb2 = (const float*)d_in[23];

    // ---- workspace (~45 MB) ----
    ushort_t* xb  = (ushort_t*)d_ws;
    ushort_t* yb  = xb + (size_t)NN*DD;
    ushort_t* zb  = yb + (size_t)NN*DD;
    ushort_t* Wf  = zb + (size_t)NN*DD;           // 11*16384 bf16
    float* SBANKS= (float*)(Wf + 11*16384);       // 8 * SBK * 256
    float* yrows = SBANKS + 8*SBK*256;            // 6*128
    int* cnt    = (int*)(yrows + 6*DD);
    int* inc    = cnt + NN;
    int* rowptr = inc + NN;                       // N+1
    int* cursor = rowptr + NN + 1;
    int* eidx   = cursor + NN;                    // E
    int* goff   = eidx + NE;                      // G+1
    int* bsum   = goff + GG + 1;
    int* boff   = bsum + NB_SCAN;

    float* out_pred   = out;
    float* out_hgraph = out + GG;
    float* out_hmeans = out + GG + GG*DD;

    const int AGG_GRID  = (NN + 15)/16;           // 3125
    const int E4_GRID   = (NE/4 + 255)/256;       // 586
    const int SETUP_GRID= (264273 + 255)/256;     // 1033
    const int GP_GRID   = GGRID + GG;             // 1294 (gemm + fused pool)

    WPtrs wp;
    for (int i = 0; i < 3; i++){
        wp.p[i]   = linW + (size_t)i*DD*DD;
        wp.p[3+i] = W1   + (size_t)i*DD*DD;
        wp.p[6+i] = W2   + (size_t)i*DD*DD;
    }
    wp.p[9] = pW1; wp.p[10] = pW2;
    const ushort_t* WfLin = Wf;
    const ushort_t* WfW1  = Wf + 3*16384;
    const ushort_t* WfW2  = Wf + 6*16384;
    const ushort_t* WfPW1 = Wf + 9*16384;
    const ushort_t* WfPW2 = Wf + 10*16384;

    float* BK0 = SBANKS + 0*SBK*256;
    float* BK1 = SBANKS + 1*SBK*256;
    float* BK5 = SBANKS + 5*SBK*256;
    float* BK6 = SBANKS + 6*SBK*256;
    float* BK7 = SBANKS + 7*SBK*256;

    // setup + CSR
    k_setup<<<SETUP_GRID, 256, 0, stream>>>(wp, Wf, bids, goff, cnt, SBANKS,
                                            emb, linW, linB, yrows);
    k_count<<<E4_GRID, 256, 0, stream>>>(dst, cnt);
    k_scanA<<<NB_SCAN, 512, 0, stream>>>(cnt, inc, bsum);
    k_scanB<<<1, 128, 0, stream>>>(bsum, boff);
    k_scanC<<<NB_SCAN, 512, 0, stream>>>(cnt, inc, boff, rowptr, cursor);
    k_fill<<<E4_GRID, 256, 0, stream>>>(src, dst, cursor, eidx);

    // ---- layer 0 ----
    k_agg0<<<AGG_GRID, 256, 0, stream>>>(d, emb, yrows, rowptr, eidx, epsA, zb);
    k_gemm<0,0,1,0><<<GGRID, 256, 0, stream>>>(zb, WfW1, nullptr, nullptr, nullptr, nullptr,
        yb, BK0, nullptr, nullptr, NN);
    k_gemm<2,0,1,0><<<GGRID, 256, 0, stream>>>(yb, WfW2, nullptr, BK0, g1, b1,
        xb, BK1, nullptr, nullptr, NN);

    // ---- layers 1,2 (lin-GEMM carries previous layer's h_means pool) ----
    for (int l = 1; l < LL; l++){
        float* pbank = SBANKS + (size_t)(2*l - 1)*SBK*256;
        float* bIn   = SBANKS + (size_t)(2*l)*SBK*256;
        float* bOut  = SBANKS + (size_t)(2*l + 1)*SBK*256;
        const float* pg = bng + (size_t)(l-1)*DD;
        const float* pb = bnb + (size_t)(l-1)*DD;

        k_gemm<2,1,0,1><<<GP_GRID, 256, 0, stream>>>(xb, WfLin + (size_t)l*16384,
            linB + (size_t)l*DD, pbank, pg, pb,
            yb, nullptr, goff, out_hmeans + (size_t)(l-1)*GG*DD, NN);
        k_agg<<<AGG_GRID, 256, 0, stream>>>(xb, yb, zb, rowptr, eidx, epsA, l, pbank, pg, pb);
        k_gemm<0,0,1,0><<<GGRID, 256, 0, stream>>>(zb, WfW1 + (size_t)l*16384, nullptr,
            nullptr, nullptr, nullptr, yb, bIn, nullptr, nullptr, NN);
        k_gemm<2,0,1,0><<<GGRID, 256, 0, stream>>>(yb, WfW2 + (size_t)l*16384, nullptr,
            bIn, g1 + (size_t)l*DD, b1 + (size_t)l*DD, xb, bOut, nullptr, nullptr, NN);
    }

    // ---- pooling MLP (pW1-GEMM carries layer-2 h_means pool) ----
    k_gemm<2,0,1,1><<<GP_GRID, 256, 0, stream>>>(xb, WfPW1, nullptr,
        BK5, bng + 2*DD, bnb + 2*DD,
        yb, BK6, goff, out_hmeans + (size_t)2*GG*DD, NN);
    k_gemm<2,0,1,0><<<GGRID, 256, 0, stream>>>(yb, WfPW2, nullptr,
        BK6, pg1, pb1, zb, BK7, nullptr, nullptr, NN);
    // h_graph pool + predict (fused)
    k_poolpred<<<GG, 256, 0, stream>>>(zb, BK7, pbng, pbnb, goff,
        prW1, prb1, prW2, prb2, out_hgraph, out_pred);
}

// Round 18
// 372.276 us; speedup vs baseline: 3.2314x; 1.0417x over previous
//
#include <hip/hip_runtime.h>

typedef unsigned short ushort_t;
typedef __attribute__((ext_vector_type(8))) short bf16x8;
typedef __attribute__((ext_vector_type(4))) float f32x4;

#define NN 50000
#define NE 600000
#define DD 128
#define LL 3
#define GG 512
#define NB_SCAN 98   // ceil(NN/512)
#define GGRID 1563   // ceil(NN/32) gemm blocks (32 rows/block)
#define SBK 32       // stats banks (atomic depth 1563 -> ~49)

__device__ __forceinline__ float b2f(ushort_t u){ return __uint_as_float(((unsigned)u)<<16); }
__device__ __forceinline__ ushort_t f2b(float f){
    unsigned x = __float_as_uint(f);
    return (ushort_t)((x + 0x7fffu + ((x>>16)&1u)) >> 16);
}

// ---- marker for host-side input-layout mismatch (f32 out) ----
__global__ void k_mark(float* __restrict__ out, float val, int n){
    int i = blockIdx.x*256 + threadIdx.x; if (i >= n) return;
    out[i] = (i == 0) ? val : 0.f;
}

// ---- fused setup: wconv + goff + zero cnt + zero banks + layer-0 LUT ----
// [0,180224) wconv | +513 goff | +50000 cnt=0 | +65536 banks=0 | +768 lin0
struct WPtrs { const float* p[11]; };
__global__ void k_setup(WPtrs wp, ushort_t* __restrict__ Wf,
                        const int* __restrict__ bids, int* __restrict__ goff,
                        int* __restrict__ cnt, float* __restrict__ banks,
                        const float* __restrict__ emb, const float* __restrict__ linW,
                        const float* __restrict__ linB, float* __restrict__ yrows){
    int idx = blockIdx.x*256 + threadIdx.x;
    if (idx < 180224){
        int m = idx >> 14, r = idx & 16383;
        int i = r & 7, l2 = (r >> 3) & 63, s = (r >> 9) & 3, n = r >> 11;
        int k   = s*32 + (l2 >> 4)*8 + i;
        int col = n*16 + (l2 & 15);
        Wf[idx] = f2b(wp.p[m][k*DD + col]);
    } else if (idx < 180737){
        int g = idx - 180224;            // 0..512
        int lo = 0, hi = NN;
        while (lo < hi){ int mid = (lo+hi) >> 1; if (bids[mid] < g) lo = mid+1; else hi = mid; }
        goff[g] = lo;
    } else if (idx < 230737){
        cnt[idx - 180737] = 0;
    } else if (idx < 296273){
        banks[idx - 230737] = 0.f;       // 8 instances * SBK * 256
    } else if (idx < 297041){
        int i = idx - 296273;            // 6*128
        int di = i >> 7, c = i & 127;
        float acc = linB[c];
        for (int k = 0; k < DD; k++) acc = fmaf(emb[di*DD + k], linW[k*DD + c], acc);
        yrows[i] = fmaxf(acc, 0.f);
    }
}

// ---------------- CSR: count (int4) ----------------
__global__ void k_count(const int* __restrict__ dst, int* __restrict__ cnt){
    int e4 = blockIdx.x*256 + threadIdx.x; if (e4 >= NE/4) return;
    int4 dv = ((const int4*)dst)[e4];
    atomicAdd(&cnt[dv.x], 1); atomicAdd(&cnt[dv.y], 1);
    atomicAdd(&cnt[dv.z], 1); atomicAdd(&cnt[dv.w], 1);
}
// ---------------- CSR: multi-block scan ----------------
__global__ void k_scanA(const int* __restrict__ cnt, int* __restrict__ inc, int* __restrict__ bsum){
    __shared__ int s[512];
    int i = blockIdx.x*512 + threadIdx.x;
    int v = (i < NN) ? cnt[i] : 0;
    s[threadIdx.x] = v; __syncthreads();
    for (int off = 1; off < 512; off <<= 1){
        int add = (threadIdx.x >= off) ? s[threadIdx.x - off] : 0;
        __syncthreads();
        s[threadIdx.x] += add;
        __syncthreads();
    }
    if (i < NN) inc[i] = s[threadIdx.x];
    if (threadIdx.x == 511) bsum[blockIdx.x] = s[511];
}
__global__ void k_scanB(const int* __restrict__ bsum, int* __restrict__ boff){
    __shared__ int s[128];
    int t = threadIdx.x;                  // 128
    int v = (t < NB_SCAN) ? bsum[t] : 0;
    s[t] = v; __syncthreads();
    for (int off = 1; off < 128; off <<= 1){
        int a = (t >= off) ? s[t - off] : 0;
        __syncthreads();
        s[t] += a;
        __syncthreads();
    }
    if (t < NB_SCAN) boff[t] = s[t] - v;
    if (t == NB_SCAN - 1) boff[NB_SCAN] = s[t];
}
__global__ void k_scanC(const int* __restrict__ cnt, const int* __restrict__ inc,
                        const int* __restrict__ boff, int* __restrict__ rowptr,
                        int* __restrict__ cursor){
    int i = blockIdx.x*512 + threadIdx.x;
    if (i < NN){
        int e = boff[blockIdx.x] + inc[i] - cnt[i];
        rowptr[i] = e; cursor[i] = e;
    } else if (i == NN){
        rowptr[NN] = NE;
    }
}
// ---------------- CSR: fill (int4 loads) ----------------
__global__ void k_fill(const int* __restrict__ src, const int* __restrict__ dst,
                       int* __restrict__ cursor, int* __restrict__ eidx){
    int e4 = blockIdx.x*256 + threadIdx.x; if (e4 >= NE/4) return;
    int4 dv = ((const int4*)dst)[e4];
    int4 sv = ((const int4*)src)[e4];
    int p0 = atomicAdd(&cursor[dv.x], 1); eidx[p0] = sv.x;
    int p1 = atomicAdd(&cursor[dv.y], 1); eidx[p1] = sv.y;
    int p2 = atomicAdd(&cursor[dv.z], 1); eidx[p2] = sv.z;
    int p3 = atomicAdd(&cursor[dv.w], 1); eidx[p3] = sv.w;
}

// ---- layer-0 aggregation from 6-row LUTs (all LDS) ----
__global__ void k_agg0(const int* __restrict__ d, const float* __restrict__ emb,
                       const float* __restrict__ yrows,
                       const int* __restrict__ rowptr, const int* __restrict__ eidx,
                       const float* __restrict__ epsP, ushort_t* __restrict__ zb){
    __shared__ float eL[6*DD], yL[6*DD];
    int t = threadIdx.x;
    for (int i = t; i < 6*DD; i += 256){ eL[i] = emb[i]; yL[i] = yrows[i]; }
    __syncthreads();
    int node = blockIdx.x*16 + (t >> 4);
    if (node >= NN) return;
    int c8 = (t & 15) << 3;
    float epl = 1.0f + epsP[0];
    int dv = d[node]; dv = dv < 0 ? 0 : (dv > 5 ? 5 : dv);
    float a[8];
#pragma unroll
    for (int i = 0; i < 8; i++) a[i] = eL[dv*DD + c8 + i] * epl;
    int e0 = rowptr[node], e1 = rowptr[node+1];
    int e = e0;
    for (; e + 3 < e1; e += 4){
        int s0 = eidx[e], s1 = eidx[e+1], s2 = eidx[e+2], s3 = eidx[e+3];
        int c0 = d[s0], c1 = d[s1], c2 = d[s2], c3 = d[s3];
        c0 = c0 < 0 ? 0 : (c0 > 5 ? 5 : c0);
        c1 = c1 < 0 ? 0 : (c1 > 5 ? 5 : c1);
        c2 = c2 < 0 ? 0 : (c2 > 5 ? 5 : c2);
        c3 = c3 < 0 ? 0 : (c3 > 5 ? 5 : c3);
#pragma unroll
        for (int i = 0; i < 8; i++)
            a[i] += (yL[c0*DD + c8 + i] + yL[c1*DD + c8 + i])
                  + (yL[c2*DD + c8 + i] + yL[c3*DD + c8 + i]);
    }
    for (; e < e1; e++){
        int s = eidx[e];
        int c = d[s]; c = c < 0 ? 0 : (c > 5 ? 5 : c);
#pragma unroll
        for (int i = 0; i < 8; i++) a[i] += yL[c*DD + c8 + i];
    }
    bf16x8 o;
#pragma unroll
    for (int i = 0; i < 8; i++) o[i] = (short)f2b(a[i]);
    *(bf16x8*)(zb + (size_t)node*DD + c8) = o;
}

// ---- aggregation layers>0: BN scale/shift from SBK-bank stats (summed in LDS) ----
__global__ void k_agg(const ushort_t* __restrict__ xb, const ushort_t* __restrict__ yb,
                      ushort_t* __restrict__ zb,
                      const int* __restrict__ rowptr, const int* __restrict__ eidx,
                      const float* __restrict__ epsP, int l,
                      const float* __restrict__ banksIn, const float* __restrict__ bng,
                      const float* __restrict__ bnb){
    __shared__ float sst[256];
    int t = threadIdx.x;
    {
        float sv = 0.f;
#pragma unroll
        for (int b = 0; b < SBK; b++) sv += banksIn[(b << 8) + t];
        sst[t] = sv;
    }
    __syncthreads();
    int node = blockIdx.x*16 + (t >> 4);
    if (node >= NN) return;
    int c8 = (t & 15) << 3;
    float epl = 1.0f + epsP[l];
    bf16x8 xr = *(const bf16x8*)(xb + (size_t)node*DD + c8);
    float a[8];
#pragma unroll
    for (int i = 0; i < 8; i++){
        int c = c8 + i;
        float mu  = sst[c] * (1.0f/NN);
        float var = sst[c + DD] * (1.0f/NN) - mu*mu;
        float sc  = rsqrtf(fmaxf(var, 0.f) + 1e-5f) * bng[c];
        float sh  = bnb[c] - mu*sc;
        a[i] = fmaxf(fmaf(b2f((ushort_t)xr[i]), sc, sh), 0.f) * epl;
    }
    int e0 = rowptr[node], e1 = rowptr[node+1];
    int e = e0;
    for (; e + 3 < e1; e += 4){
        int s0 = eidx[e], s1 = eidx[e+1], s2 = eidx[e+2], s3 = eidx[e+3];
        bf16x8 v0 = *(const bf16x8*)(yb + (size_t)s0*DD + c8);
        bf16x8 v1 = *(const bf16x8*)(yb + (size_t)s1*DD + c8);
        bf16x8 v2 = *(const bf16x8*)(yb + (size_t)s2*DD + c8);
        bf16x8 v3 = *(const bf16x8*)(yb + (size_t)s3*DD + c8);
#pragma unroll
        for (int i = 0; i < 8; i++)
            a[i] += (b2f((ushort_t)v0[i]) + b2f((ushort_t)v1[i]))
                  + (b2f((ushort_t)v2[i]) + b2f((ushort_t)v3[i]));
    }
    for (; e < e1; e++){
        int s = eidx[e];
        bf16x8 v = *(const bf16x8*)(yb + (size_t)s*DD + c8);
#pragma unroll
        for (int i = 0; i < 8; i++) a[i] += b2f((ushort_t)v[i]);
    }
    bf16x8 o;
#pragma unroll
    for (int i = 0; i < 8; i++) o[i] = (short)f2b(a[i]);
    *(bf16x8*)(zb + (size_t)node*DD + c8) = o;
}

// ---------------- MFMA GEMM: 32 rows x 128 cols, 4 waves (2 row x 2 col) + banked stats ----
// AMODE 2: A'=relu(bn(A)) from SBK-bank sum.  OMODE 1: relu(C+bias).
// STATS: per-block column sum/sumsq -> bank atomic (bank = blockIdx & (SBK-1)).
// POOL: blocks >= GGRID do graph-pool of A using banked stats.
template<int AMODE, int OMODE, int STATS, int POOL>
__global__ __launch_bounds__(256) void k_gemm(
    const ushort_t* __restrict__ A, const ushort_t* __restrict__ Wf,
    const float* __restrict__ bias,
    const float* __restrict__ banksIn, const float* __restrict__ bng,
    const float* __restrict__ bnb,
    ushort_t* __restrict__ C, float* __restrict__ banksOut,
    const int* __restrict__ goff, float* __restrict__ pool_out, int M)
{
    __shared__ float ssl[256];
    __shared__ float sred[256];
    __shared__ ushort_t lrep[32*132];
    const int t = threadIdx.x;

    if (POOL && blockIdx.x >= GGRID){
        int g = blockIdx.x - GGRID;
        {
            float sv = 0.f;
#pragma unroll
            for (int b = 0; b < SBK; b++) sv += banksIn[(b << 8) + t];
            ssl[t] = sv;
        }
        __syncthreads();
        int c = t & 127, hf = t >> 7;
        float mu  = ssl[c] * (1.0f/NN);
        float var = ssl[c + DD] * (1.0f/NN) - mu*mu;
        float sc  = rsqrtf(fmaxf(var, 0.f) + 1e-5f) * bng[c];
        float sh  = bnb[c] - mu*sc;
        int r0 = goff[g], r1 = goff[g+1];
        float acc = 0.f;
        for (int r = r0 + hf; r < r1; r += 2)
            acc += fmaxf(fmaf(b2f(A[(size_t)r*DD + c]), sc, sh), 0.f);
        sred[t] = acc; __syncthreads();
        if (t < 128)
            pool_out[g*DD + t] = (sred[t] + sred[t+128]) / fmaxf((float)(r1 - r0), 1.0f);
        return;
    }

    const int w = t >> 6, l = t & 63;
    const int rw = w >> 1, cw = w & 1;       // row-tile, col-tile
    const int rowBlk = blockIdx.x*32, rowBase = rowBlk + rw*16;
    const int lm = l & 15, kg = l >> 4;

    if (AMODE == 2){
        float sv = 0.f;
#pragma unroll
        for (int b = 0; b < SBK; b++) sv += banksIn[(b << 8) + t];
        ssl[t] = sv;
        __syncthreads();
        if (t < 128){
            float mu  = ssl[t] * (1.0f/NN);
            float var = ssl[t + DD] * (1.0f/NN) - mu*mu;
            float sc  = rsqrtf(fmaxf(var, 0.f) + 1e-5f) * bng[t];
            ssl[t] = sc;
            ssl[t + DD] = bnb[t] - mu*sc;
        }
    }
    if (STATS) sred[t] = 0.f;
    if (AMODE == 2 || STATS) __syncthreads();

    f32x4 acc[4];
#pragma unroll
    for (int n = 0; n < 4; n++) acc[n] = (f32x4){0.f,0.f,0.f,0.f};

    int arow = rowBase + lm;
    if (arow >= M) arow = M - 1;
    const ushort_t* aptr = A + (size_t)arow*DD + kg*8;

#pragma unroll
    for (int s = 0; s < 4; s++){
        bf16x8 af;
        if (AMODE == 0){
            af = *(const bf16x8*)(aptr + s*32);
        } else {
            bf16x8 ar = *(const bf16x8*)(aptr + s*32);
            int k0 = s*32 + kg*8;
#pragma unroll
            for (int i = 0; i < 8; i++){
                float v = b2f((ushort_t)ar[i]);
                v = fmaxf(fmaf(v, ssl[k0+i], ssl[DD+k0+i]), 0.f);
                ((ushort_t*)&af)[i] = f2b(v);
            }
        }
#pragma unroll
        for (int n = 0; n < 4; n++){
            int nc = cw*4 + n;
            bf16x8 bfr = *(const bf16x8*)(Wf + (size_t)((nc*4 + s)*64 + l)*8);
            acc[n] = __builtin_amdgcn_mfma_f32_16x16x32_bf16(af, bfr, acc[n], 0, 0, 0);
        }
    }

    // transform + stats + bf16 LDS repack (D: col=(cw*4+n)*16+lm, row=rw*16+kg*4+j)
#pragma unroll
    for (int n = 0; n < 4; n++){
        int col = (cw*4 + n)*16 + lm;
        float cs = 0.f, cq = 0.f;
#pragma unroll
        for (int j = 0; j < 4; j++){
            float v = acc[n][j];
            if (OMODE == 1) v = fmaxf(v + bias[col], 0.f);
            lrep[(rw*16 + kg*4 + j)*132 + col] = f2b(v);
            if (STATS && (rowBase + kg*4 + j) < M){ cs += v; cq += v*v; }
        }
        if (STATS){
            cs += __shfl_xor(cs, 16); cs += __shfl_xor(cs, 32);
            cq += __shfl_xor(cq, 16); cq += __shfl_xor(cq, 32);
            if (kg == 0){
                atomicAdd(&sred[col], cs);
                atomicAdd(&sred[col + DD], cq);
            }
        }
    }
    __syncthreads();

    // coalesced store: thread t -> local row t>>3, 16-ushort segment (t&7)
    {
        int lr = t >> 3;
        int gr = rowBlk + lr;
        if (gr < M){
            int seg = (t & 7) * 16;
            const ushort_t* lp = lrep + lr*132 + seg;
            bf16x8 o0 = *(const bf16x8*)(lp);
            bf16x8 o1 = *(const bf16x8*)(lp + 8);
            ushort_t* cp = C + (size_t)gr*DD + seg;
            *(bf16x8*)(cp)     = o0;
            *(bf16x8*)(cp + 8) = o1;
        }
    }

    if (STATS){
        __syncthreads();
        atomicAdd(&banksOut[((blockIdx.x & (SBK-1)) << 8) + t], sred[t]);
    }
}

// ---------------- fused h_graph pool + predict head (banked stats in) ----------------
__global__ __launch_bounds__(256) void k_poolpred(const ushort_t* __restrict__ zb,
        const float* __restrict__ banksIn, const float* __restrict__ bng,
        const float* __restrict__ bnb, const int* __restrict__ goff,
        const float* __restrict__ W1, const float* __restrict__ b1,
        const float* __restrict__ W2, const float* __restrict__ b2,
        float* __restrict__ out_hgraph, float* __restrict__ out_pred){
    __shared__ float hrow[DD];
    __shared__ float pr[256];
    int g = blockIdx.x, t = threadIdx.x;
    {
        float sv = 0.f;
#pragma unroll
        for (int b = 0; b < SBK; b++) sv += banksIn[(b << 8) + t];
        pr[t] = sv;
    }
    __syncthreads();
    int c = t & 127, hf = t >> 7;
    float mu  = pr[c] * (1.0f/NN);
    float var = pr[c + DD] * (1.0f/NN) - mu*mu;
    float sc  = rsqrtf(fmaxf(var, 0.f) + 1e-5f) * bng[c];
    float sh  = bnb[c] - mu*sc;
    __syncthreads();
    int r0 = goff[g], r1 = goff[g+1];
    float acc = 0.f;
    for (int r = r0 + hf; r < r1; r += 2)
        acc += fmaxf(fmaf(b2f(zb[(size_t)r*DD + c]), sc, sh), 0.f);
    pr[t] = acc; __syncthreads();
    if (t < 128){
        float m = (pr[t] + pr[t+128]) / fmaxf((float)(r1 - r0), 1.0f);
        hrow[t] = m;
        out_hgraph[g*DD + t] = m;
    }
    __syncthreads();
    float a2 = b1[t];
    for (int k = 0; k < DD; k++) a2 = fmaf(hrow[k], W1[k*256 + t], a2);
    pr[t] = fmaxf(a2, 0.f) * W2[t];
    __syncthreads();
    for (int off = 128; off > 0; off >>= 1){
        if (t < off) pr[t] += pr[t + off];
        __syncthreads();
    }
    if (t == 0) out_pred[g] = pr[0] + b2[0];
}

extern "C" void kernel_launch(void* const* d_in, const int* in_sizes, int n_in,
                              void* d_out, int out_size, void* d_ws, size_t ws_size,
                              hipStream_t stream){
    float* out = (float*)d_out;
    const int OUT_N = GG + GG*DD + LL*GG*DD;      // 262656

    static const int EXP[24] = {50000,600000,600000,50000, 768,49152,384,49152,384,384,
                                49152,3,384,384,16384,128,128,16384,128,128,
                                32768,256,256,1};
    int bad = -1;
    if (n_in != 24) bad = 50;
    else for (int i = 0; i < 24; i++) if (in_sizes[i] != EXP[i]) { bad = i; break; }
    if (bad >= 0){
        k_mark<<<(OUT_N+255)/256, 256, 0, stream>>>(out, 2048.0f + (float)bad, OUT_N);
        return;
    }

    const int* d    = (const int*)d_in[0];
    const int* src  = (const int*)d_in[1];
    const int* dst  = (const int*)d_in[2];
    const int* bids = (const int*)d_in[3];
    const float* emb  = (const float*)d_in[4];
    const float* linW = (const float*)d_in[5];
    const float* linB = (const float*)d_in[6];
    const float* W1   = (const float*)d_in[7];
    const float* g1   = (const float*)d_in[8];
    const float* b1   = (const float*)d_in[9];
    const float* W2   = (const float*)d_in[10];
    const float* epsA = (const float*)d_in[11];
    const float* bng  = (const float*)d_in[12];
    const float* bnb  = (const float*)d_in[13];
    const float* pW1  = (const float*)d_in[14];
    const float* pg1  = (const float*)d_in[15];
    const float* pb1  = (const float*)d_in[16];
    const float* pW2  = (const float*)d_in[17];
    const float* pbng = (const float*)d_in[18];
    const float* pbnb = (const float*)d_in[19];
    const float* prW1 = (const float*)d_in[20];
    const float* prb1 = (const float*)d_in[21];
    const float* prW2 = (const float*)d_in[22];
    const float* prb2 = (const float*)d_in[23];

    // ---- workspace (~45 MB) ----
    ushort_t* xb  = (ushort_t*)d_ws;
    ushort_t* yb  = xb + (size_t)NN*DD;
    ushort_t* zb  = yb + (size_t)NN*DD;
    ushort_t* Wf  = zb + (size_t)NN*DD;           // 11*16384 bf16
    float* SBANKS= (float*)(Wf + 11*16384);       // 8 * SBK * 256
    float* yrows = SBANKS + 8*SBK*256;            // 6*128
    int* cnt    = (int*)(yrows + 6*DD);
    int* inc    = cnt + NN;
    int* rowptr = inc + NN;                       // N+1
    int* cursor = rowptr + NN + 1;
    int* eidx   = cursor + NN;                    // E
    int* goff   = eidx + NE;                      // G+1
    int* bsum   = goff + GG + 1;
    int* boff   = bsum + NB_SCAN;

    float* out_pred   = out;
    float* out_hgraph = out + GG;
    float* out_hmeans = out + GG + GG*DD;

    const int AGG_GRID  = (NN + 15)/16;           // 3125
    const int E4_GRID   = (NE/4 + 255)/256;       // 586
    const int SETUP_GRID= (297041 + 255)/256;     // 1161
    const int GP_GRID   = GGRID + GG;             // 2075 (gemm + fused pool)

    WPtrs wp;
    for (int i = 0; i < 3; i++){
        wp.p[i]   = linW + (size_t)i*DD*DD;
        wp.p[3+i] = W1   + (size_t)i*DD*DD;
        wp.p[6+i] = W2   + (size_t)i*DD*DD;
    }
    wp.p[9] = pW1; wp.p[10] = pW2;
    const ushort_t* WfLin = Wf;
    const ushort_t* WfW1  = Wf + 3*16384;
    const ushort_t* WfW2  = Wf + 6*16384;
    const ushort_t* WfPW1 = Wf + 9*16384;
    const ushort_t* WfPW2 = Wf + 10*16384;

    float* BK0 = SBANKS + 0*SBK*256;
    float* BK1 = SBANKS + 1*SBK*256;
    float* BK5 = SBANKS + 5*SBK*256;
    float* BK6 = SBANKS + 6*SBK*256;
    float* BK7 = SBANKS + 7*SBK*256;

    // setup + CSR
    k_setup<<<SETUP_GRID, 256, 0, stream>>>(wp, Wf, bids, goff, cnt, SBANKS,
                                            emb, linW, linB, yrows);
    k_count<<<E4_GRID, 256, 0, stream>>>(dst, cnt);
    k_scanA<<<NB_SCAN, 512, 0, stream>>>(cnt, inc, bsum);
    k_scanB<<<1, 128, 0, stream>>>(bsum, boff);
    k_scanC<<<NB_SCAN, 512, 0, stream>>>(cnt, inc, boff, rowptr, cursor);
    k_fill<<<E4_GRID, 256, 0, stream>>>(src, dst, cursor, eidx);

    // ---- layer 0 ----
    k_agg0<<<AGG_GRID, 256, 0, stream>>>(d, emb, yrows, rowptr, eidx, epsA, zb);
    k_gemm<0,0,1,0><<<GGRID, 256, 0, stream>>>(zb, WfW1, nullptr, nullptr, nullptr, nullptr,
        yb, BK0, nullptr, nullptr, NN);
    k_gemm<2,0,1,0><<<GGRID, 256, 0, stream>>>(yb, WfW2, nullptr, BK0, g1, b1,
        xb, BK1, nullptr, nullptr, NN);

    // ---- layers 1,2 (lin-GEMM carries previous layer's h_means pool) ----
    for (int l = 1; l < LL; l++){
        float* pbank = SBANKS + (size_t)(2*l - 1)*SBK*256;
        float* bIn   = SBANKS + (size_t)(2*l)*SBK*256;
        float* bOut  = SBANKS + (size_t)(2*l + 1)*SBK*256;
        const float* pg = bng + (size_t)(l-1)*DD;
        const float* pb = bnb + (size_t)(l-1)*DD;

        k_gemm<2,1,0,1><<<GP_GRID, 256, 0, stream>>>(xb, WfLin + (size_t)l*16384,
            linB + (size_t)l*DD, pbank, pg, pb,
            yb, nullptr, goff, out_hmeans + (size_t)(l-1)*GG*DD, NN);
        k_agg<<<AGG_GRID, 256, 0, stream>>>(xb, yb, zb, rowptr, eidx, epsA, l, pbank, pg, pb);
        k_gemm<0,0,1,0><<<GGRID, 256, 0, stream>>>(zb, WfW1 + (size_t)l*16384, nullptr,
            nullptr, nullptr, nullptr, yb, bIn, nullptr, nullptr, NN);
        k_gemm<2,0,1,0><<<GGRID, 256, 0, stream>>>(yb, WfW2 + (size_t)l*16384, nullptr,
            bIn, g1 + (size_t)l*DD, b1 + (size_t)l*DD, xb, bOut, nullptr, nullptr, NN);
    }

    // ---- pooling MLP (pW1-GEMM carries layer-2 h_means pool) ----
    k_gemm<2,0,1,1><<<GP_GRID, 256, 0, stream>>>(xb, WfPW1, nullptr,
        BK5, bng + 2*DD, bnb + 2*DD,
        yb, BK6, goff, out_hmeans + (size_t)2*GG*DD, NN);
    k_gemm<2,0,1,0><<<GGRID, 256, 0, stream>>>(yb, WfPW2, nullptr,
        BK6, pg1, pb1, zb, BK7, nullptr, nullptr, NN);
    // h_graph pool + predict (fused)
    k_poolpred<<<GG, 256, 0, stream>>>(zb, BK7, pbng, pbnb, goff,
        prW1, prb1, prW2, prb2, out_hgraph, out_pred);
}

// Round 19
// 358.041 us; speedup vs baseline: 3.3599x; 1.0398x over previous
//
#include <hip/hip_runtime.h>

typedef unsigned short ushort_t;
typedef __attribute__((ext_vector_type(8))) short bf16x8;
typedef __attribute__((ext_vector_type(4))) float f32x4;

#define NN 50000
#define NE 600000
#define DD 128
#define LL 3
#define GG 512
#define NB_SCAN 98   // ceil(NN/512)
#define GGRID 1563   // ceil(NN/32) gemm blocks (32 rows/block)
#define SBK 32       // stats banks

__device__ __forceinline__ float b2f(ushort_t u){ return __uint_as_float(((unsigned)u)<<16); }
__device__ __forceinline__ ushort_t f2b(float f){
    unsigned x = __float_as_uint(f);
    return (ushort_t)((x + 0x7fffu + ((x>>16)&1u)) >> 16);
}

// ---- marker for host-side input-layout mismatch (f32 out) ----
__global__ void k_mark(float* __restrict__ out, float val, int n){
    int i = blockIdx.x*256 + threadIdx.x; if (i >= n) return;
    out[i] = (i == 0) ? val : 0.f;
}

// ---- fused setup: wconv + goff + zero cnt + zero banks + layer-0 LUT ----
struct WPtrs { const float* p[11]; };
__global__ void k_setup(WPtrs wp, ushort_t* __restrict__ Wf,
                        const int* __restrict__ bids, int* __restrict__ goff,
                        int* __restrict__ cnt, float* __restrict__ banks,
                        const float* __restrict__ emb, const float* __restrict__ linW,
                        const float* __restrict__ linB, float* __restrict__ yrows){
    int idx = blockIdx.x*256 + threadIdx.x;
    if (idx < 180224){
        int m = idx >> 14, r = idx & 16383;
        int i = r & 7, l2 = (r >> 3) & 63, s = (r >> 9) & 3, n = r >> 11;
        int k   = s*32 + (l2 >> 4)*8 + i;
        int col = n*16 + (l2 & 15);
        Wf[idx] = f2b(wp.p[m][k*DD + col]);
    } else if (idx < 180737){
        int g = idx - 180224;            // 0..512
        int lo = 0, hi = NN;
        while (lo < hi){ int mid = (lo+hi) >> 1; if (bids[mid] < g) lo = mid+1; else hi = mid; }
        goff[g] = lo;
    } else if (idx < 230737){
        cnt[idx - 180737] = 0;
    } else if (idx < 296273){
        banks[idx - 230737] = 0.f;       // 8 instances * SBK * 256
    } else if (idx < 297041){
        int i = idx - 296273;            // 6*128
        int di = i >> 7, c = i & 127;
        float acc = linB[c];
        for (int k = 0; k < DD; k++) acc = fmaf(emb[di*DD + k], linW[k*DD + c], acc);
        yrows[i] = fmaxf(acc, 0.f);
    }
}

// ---------------- CSR: count (int4) ----------------
__global__ void k_count(const int* __restrict__ dst, int* __restrict__ cnt){
    int e4 = blockIdx.x*256 + threadIdx.x; if (e4 >= NE/4) return;
    int4 dv = ((const int4*)dst)[e4];
    atomicAdd(&cnt[dv.x], 1); atomicAdd(&cnt[dv.y], 1);
    atomicAdd(&cnt[dv.z], 1); atomicAdd(&cnt[dv.w], 1);
}
// ---------------- CSR: scanA (per-block inclusive) ----------------
__global__ void k_scanA(const int* __restrict__ cnt, int* __restrict__ inc, int* __restrict__ bsum){
    __shared__ int s[512];
    int i = blockIdx.x*512 + threadIdx.x;
    int v = (i < NN) ? cnt[i] : 0;
    s[threadIdx.x] = v; __syncthreads();
    for (int off = 1; off < 512; off <<= 1){
        int add = (threadIdx.x >= off) ? s[threadIdx.x - off] : 0;
        __syncthreads();
        s[threadIdx.x] += add;
        __syncthreads();
    }
    if (i < NN) inc[i] = s[threadIdx.x];
    if (threadIdx.x == 511) bsum[blockIdx.x] = s[511];
}
// ---------------- CSR: scanC (block offset computed in-block from bsum) ----------------
__global__ void k_scanC(const int* __restrict__ cnt, const int* __restrict__ inc,
                        const int* __restrict__ bsum, int* __restrict__ rowptr,
                        int* __restrict__ cursor){
    __shared__ int sb[128];
    int t = threadIdx.x;                 // 512
    if (t < 128) sb[t] = (t < NB_SCAN) ? bsum[t] : 0;
    __syncthreads();
    for (int off = 1; off < 128; off <<= 1){
        int a = (t < 128 && t >= off) ? sb[t - off] : 0;
        __syncthreads();
        if (t < 128) sb[t] += a;
        __syncthreads();
    }
    int myoff = (blockIdx.x == 0) ? 0 : sb[blockIdx.x - 1];
    int i = blockIdx.x*512 + t;
    if (i < NN){
        int e = myoff + inc[i] - cnt[i];
        rowptr[i] = e; cursor[i] = e;
    } else if (i == NN){
        rowptr[NN] = NE;
    }
}
// ---------------- CSR: fill (int4 loads) ----------------
__global__ void k_fill(const int* __restrict__ src, const int* __restrict__ dst,
                       int* __restrict__ cursor, int* __restrict__ eidx){
    int e4 = blockIdx.x*256 + threadIdx.x; if (e4 >= NE/4) return;
    int4 dv = ((const int4*)dst)[e4];
    int4 sv = ((const int4*)src)[e4];
    int p0 = atomicAdd(&cursor[dv.x], 1); eidx[p0] = sv.x;
    int p1 = atomicAdd(&cursor[dv.y], 1); eidx[p1] = sv.y;
    int p2 = atomicAdd(&cursor[dv.z], 1); eidx[p2] = sv.z;
    int p3 = atomicAdd(&cursor[dv.w], 1); eidx[p3] = sv.w;
}

// ---------------- MFMA GEMM: 32 rows x 128 cols, 4 waves, banked stats ----------------
// AM: 0 plain A | 2 A'=relu(bn(A)) | 3 A'=gather z=relu(bn(A))*(1+eps)+sum msg[src]
//     4 A'=layer0 gather z=emb[d[row]]*(1+eps)+sum yrows[d[src]] (LUTs in LDS)
// OM: 0 plain | 1 relu(C+bias).  ST: column stats -> bank atomic.
// POOL: blocks >= GGRID do graph-pool of A using banksIn.
template<int AM, int OM, int ST, int POOL>
__global__ __launch_bounds__(256) void k_gemm(
    const ushort_t* __restrict__ A, const ushort_t* __restrict__ Wf,
    const float* __restrict__ bias,
    const float* __restrict__ banksIn, const float* __restrict__ bng,
    const float* __restrict__ bnb,
    const ushort_t* __restrict__ msg,
    const int* __restrict__ rowptr, const int* __restrict__ eidx,
    const int* __restrict__ darr, const float* __restrict__ emb6,
    const float* __restrict__ yrows, const float* __restrict__ epsP, int lidx,
    ushort_t* __restrict__ C, float* __restrict__ banksOut,
    const int* __restrict__ goff, float* __restrict__ pool_out, int M)
{
    __shared__ float ssl[256];
    __shared__ float sred[256];
    __shared__ ushort_t lrep[32*132];
    __shared__ ushort_t zlds[(AM >= 3) ? 32*132 : 1];
    __shared__ float luts[(AM == 4) ? 2*6*132 : 1];   // yL | eL
    const int t = threadIdx.x;

    if (POOL && blockIdx.x >= GGRID){
        int g = blockIdx.x - GGRID;
        {
            float sv = 0.f;
#pragma unroll
            for (int b = 0; b < SBK; b++) sv += banksIn[(b << 8) + t];
            ssl[t] = sv;
        }
        __syncthreads();
        int c = t & 127, hf = t >> 7;
        float mu  = ssl[c] * (1.0f/NN);
        float var = ssl[c + DD] * (1.0f/NN) - mu*mu;
        float sc  = rsqrtf(fmaxf(var, 0.f) + 1e-5f) * bng[c];
        float sh  = bnb[c] - mu*sc;
        int r0 = goff[g], r1 = goff[g+1];
        float acc = 0.f;
        for (int r = r0 + hf; r < r1; r += 2)
            acc += fmaxf(fmaf(b2f(A[(size_t)r*DD + c]), sc, sh), 0.f);
        sred[t] = acc; __syncthreads();
        if (t < 128)
            pool_out[g*DD + t] = (sred[t] + sred[t+128]) / fmaxf((float)(r1 - r0), 1.0f);
        return;
    }

    const int w = t >> 6, l = t & 63;
    const int rw = w >> 1, cw = w & 1;
    const int rowBlk = blockIdx.x*32, rowBase = rowBlk + rw*16;
    const int lm = l & 15, kg = l >> 4;

    if (AM == 2 || AM == 3){
        float sv = 0.f;
#pragma unroll
        for (int b = 0; b < SBK; b++) sv += banksIn[(b << 8) + t];
        ssl[t] = sv;
        __syncthreads();
        if (t < 128){
            float mu  = ssl[t] * (1.0f/NN);
            float var = ssl[t + DD] * (1.0f/NN) - mu*mu;
            float sc  = rsqrtf(fmaxf(var, 0.f) + 1e-5f) * bng[t];
            ssl[t] = sc;
            ssl[t + DD] = bnb[t] - mu*sc;
        }
    }
    if (AM == 4){
        for (int i = t; i < 6*DD; i += 256){
            int r6 = i >> 7, c = i & 127;
            luts[r6*132 + c]         = yrows[i];
            luts[6*132 + r6*132 + c] = emb6[i];
        }
    }
    if (ST) sred[t] = 0.f;
    __syncthreads();

    // ---- gather phase (AM 3/4): 8 threads/row build z in LDS ----
    if (AM == 3 || AM == 4){
        int row  = t >> 3;               // 0..31
        int cseg = (t & 7) * 16;         // 16 cols
        int grow = rowBlk + row; if (grow >= M) grow = M - 1;
        float epl = 1.0f + epsP[lidx];
        float z[16];
        if (AM == 3){
            const ushort_t* xp = A + (size_t)grow*DD + cseg;
            bf16x8 x0 = *(const bf16x8*)(xp);
            bf16x8 x1 = *(const bf16x8*)(xp + 8);
#pragma unroll
            for (int i = 0; i < 8; i++){
                z[i]   = fmaxf(fmaf(b2f((ushort_t)x0[i]), ssl[cseg+i],   ssl[DD+cseg+i]),   0.f) * epl;
                z[8+i] = fmaxf(fmaf(b2f((ushort_t)x1[i]), ssl[cseg+8+i], ssl[DD+cseg+8+i]), 0.f) * epl;
            }
        } else {
            int dv = darr[grow]; dv = dv < 0 ? 0 : (dv > 5 ? 5 : dv);
            const float* ep = luts + 6*132 + dv*132 + cseg;
#pragma unroll
            for (int i = 0; i < 16; i++) z[i] = ep[i] * epl;
        }
        int e0 = rowptr[grow], e1 = rowptr[grow+1];
        if (AM == 3){
            int e = e0;
            for (; e + 1 < e1; e += 2){
                int s0 = eidx[e], s1 = eidx[e+1];
                const ushort_t* m0 = msg + (size_t)s0*DD + cseg;
                const ushort_t* m1 = msg + (size_t)s1*DD + cseg;
                bf16x8 a0 = *(const bf16x8*)(m0), a1 = *(const bf16x8*)(m0 + 8);
                bf16x8 b0 = *(const bf16x8*)(m1), b1 = *(const bf16x8*)(m1 + 8);
#pragma unroll
                for (int i = 0; i < 8; i++){
                    z[i]   += b2f((ushort_t)a0[i]) + b2f((ushort_t)b0[i]);
                    z[8+i] += b2f((ushort_t)a1[i]) + b2f((ushort_t)b1[i]);
                }
            }
            for (; e < e1; e++){
                int s0 = eidx[e];
                const ushort_t* m0 = msg + (size_t)s0*DD + cseg;
                bf16x8 a0 = *(const bf16x8*)(m0), a1 = *(const bf16x8*)(m0 + 8);
#pragma unroll
                for (int i = 0; i < 8; i++){
                    z[i]   += b2f((ushort_t)a0[i]);
                    z[8+i] += b2f((ushort_t)a1[i]);
                }
            }
        } else {
            for (int e = e0; e < e1; e++){
                int di = darr[eidx[e]]; di = di < 0 ? 0 : (di > 5 ? 5 : di);
                const float* yp = luts + di*132 + cseg;
#pragma unroll
                for (int i = 0; i < 16; i++) z[i] += yp[i];
            }
        }
        ushort_t* zp = zlds + row*132 + cseg;
#pragma unroll
        for (int i = 0; i < 16; i++) zp[i] = f2b(z[i]);
        __syncthreads();
    }

    f32x4 acc[4];
#pragma unroll
    for (int n = 0; n < 4; n++) acc[n] = (f32x4){0.f,0.f,0.f,0.f};

    int arow = rowBase + lm;
    if (arow >= M) arow = M - 1;

    bf16x8 af[4];
    if (AM == 3 || AM == 4){
        const ushort_t* zp = zlds + (rw*16 + lm)*132 + kg*8;
#pragma unroll
        for (int s = 0; s < 4; s++) af[s] = *(const bf16x8*)(zp + s*32);
    } else {
        const ushort_t* aptr = A + (size_t)arow*DD + kg*8;
#pragma unroll
        for (int s = 0; s < 4; s++){
            bf16x8 ar = *(const bf16x8*)(aptr + s*32);
            if (AM == 0){
                af[s] = ar;
            } else {
                int k0 = s*32 + kg*8;
#pragma unroll
                for (int i = 0; i < 8; i++){
                    float v = b2f((ushort_t)ar[i]);
                    v = fmaxf(fmaf(v, ssl[k0+i], ssl[DD+k0+i]), 0.f);
                    ((ushort_t*)&af[s])[i] = f2b(v);
                }
            }
        }
    }

#pragma unroll
    for (int s = 0; s < 4; s++){
#pragma unroll
        for (int n = 0; n < 4; n++){
            int nc = cw*4 + n;
            bf16x8 bfr = *(const bf16x8*)(Wf + (size_t)((nc*4 + s)*64 + l)*8);
            acc[n] = __builtin_amdgcn_mfma_f32_16x16x32_bf16(af[s], bfr, acc[n], 0, 0, 0);
        }
    }

    // transform + stats + bf16 LDS repack
#pragma unroll
    for (int n = 0; n < 4; n++){
        int col = (cw*4 + n)*16 + lm;
        float cs = 0.f, cq = 0.f;
#pragma unroll
        for (int j = 0; j < 4; j++){
            float v = acc[n][j];
            if (OM == 1) v = fmaxf(v + bias[col], 0.f);
            lrep[(rw*16 + kg*4 + j)*132 + col] = f2b(v);
            if (ST && (rowBase + kg*4 + j) < M){ cs += v; cq += v*v; }
        }
        if (ST){
            cs += __shfl_xor(cs, 16); cs += __shfl_xor(cs, 32);
            cq += __shfl_xor(cq, 16); cq += __shfl_xor(cq, 32);
            if (kg == 0){
                atomicAdd(&sred[col], cs);
                atomicAdd(&sred[col + DD], cq);
            }
        }
    }
    __syncthreads();

    // coalesced store
    {
        int lr = t >> 3;
        int gr = rowBlk + lr;
        if (gr < M){
            int seg = (t & 7) * 16;
            const ushort_t* lp = lrep + lr*132 + seg;
            bf16x8 o0 = *(const bf16x8*)(lp);
            bf16x8 o1 = *(const bf16x8*)(lp + 8);
            ushort_t* cp = C + (size_t)gr*DD + seg;
            *(bf16x8*)(cp)     = o0;
            *(bf16x8*)(cp + 8) = o1;
        }
    }

    if (ST){
        __syncthreads();
        atomicAdd(&banksOut[((blockIdx.x & (SBK-1)) << 8) + t], sred[t]);
    }
}

// ---------------- fused h_graph pool + predict head (banked stats in) ----------------
__global__ __launch_bounds__(256) void k_poolpred(const ushort_t* __restrict__ zb,
        const float* __restrict__ banksIn, const float* __restrict__ bng,
        const float* __restrict__ bnb, const int* __restrict__ goff,
        const float* __restrict__ W1, const float* __restrict__ b1,
        const float* __restrict__ W2, const float* __restrict__ b2,
        float* __restrict__ out_hgraph, float* __restrict__ out_pred){
    __shared__ float hrow[DD];
    __shared__ float pr[256];
    int g = blockIdx.x, t = threadIdx.x;
    {
        float sv = 0.f;
#pragma unroll
        for (int b = 0; b < SBK; b++) sv += banksIn[(b << 8) + t];
        pr[t] = sv;
    }
    __syncthreads();
    int c = t & 127, hf = t >> 7;
    float mu  = pr[c] * (1.0f/NN);
    float var = pr[c + DD] * (1.0f/NN) - mu*mu;
    float sc  = rsqrtf(fmaxf(var, 0.f) + 1e-5f) * bng[c];
    float sh  = bnb[c] - mu*sc;
    __syncthreads();
    int r0 = goff[g], r1 = goff[g+1];
    float acc = 0.f;
    for (int r = r0 + hf; r < r1; r += 2)
        acc += fmaxf(fmaf(b2f(zb[(size_t)r*DD + c]), sc, sh), 0.f);
    pr[t] = acc; __syncthreads();
    if (t < 128){
        float m = (pr[t] + pr[t+128]) / fmaxf((float)(r1 - r0), 1.0f);
        hrow[t] = m;
        out_hgraph[g*DD + t] = m;
    }
    __syncthreads();
    float a2 = b1[t];
    for (int k = 0; k < DD; k++) a2 = fmaf(hrow[k], W1[k*256 + t], a2);
    pr[t] = fmaxf(a2, 0.f) * W2[t];
    __syncthreads();
    for (int off = 128; off > 0; off >>= 1){
        if (t < off) pr[t] += pr[t + off];
        __syncthreads();
    }
    if (t == 0) out_pred[g] = pr[0] + b2[0];
}

extern "C" void kernel_launch(void* const* d_in, const int* in_sizes, int n_in,
                              void* d_out, int out_size, void* d_ws, size_t ws_size,
                              hipStream_t stream){
    float* out = (float*)d_out;
    const int OUT_N = GG + GG*DD + LL*GG*DD;      // 262656

    static const int EXP[24] = {50000,600000,600000,50000, 768,49152,384,49152,384,384,
                                49152,3,384,384,16384,128,128,16384,128,128,
                                32768,256,256,1};
    int bad = -1;
    if (n_in != 24) bad = 50;
    else for (int i = 0; i < 24; i++) if (in_sizes[i] != EXP[i]) { bad = i; break; }
    if (bad >= 0){
        k_mark<<<(OUT_N+255)/256, 256, 0, stream>>>(out, 2048.0f + (float)bad, OUT_N);
        return;
    }

    const int* d    = (const int*)d_in[0];
    const int* src  = (const int*)d_in[1];
    const int* dst  = (const int*)d_in[2];
    const int* bids = (const int*)d_in[3];
    const float* emb  = (const float*)d_in[4];
    const float* linW = (const float*)d_in[5];
    const float* linB = (const float*)d_in[6];
    const float* W1   = (const float*)d_in[7];
    const float* g1   = (const float*)d_in[8];
    const float* b1   = (const float*)d_in[9];
    const float* W2   = (const float*)d_in[10];
    const float* epsA = (const float*)d_in[11];
    const float* bng  = (const float*)d_in[12];
    const float* bnb  = (const float*)d_in[13];
    const float* pW1  = (const float*)d_in[14];
    const float* pg1  = (const float*)d_in[15];
    const float* pb1  = (const float*)d_in[16];
    const float* pW2  = (const float*)d_in[17];
    const float* pbng = (const float*)d_in[18];
    const float* pbnb = (const float*)d_in[19];
    const float* prW1 = (const float*)d_in[20];
    const float* prb1 = (const float*)d_in[21];
    const float* prW2 = (const float*)d_in[22];
    const float* prb2 = (const float*)d_in[23];

    // ---- workspace ----
    ushort_t* xb  = (ushort_t*)d_ws;
    ushort_t* yb  = xb + (size_t)NN*DD;
    ushort_t* zb  = yb + (size_t)NN*DD;
    ushort_t* Wf  = zb + (size_t)NN*DD;           // 11*16384 bf16
    float* SBANKS= (float*)(Wf + 11*16384);       // 8 * SBK * 256
    float* yrows = SBANKS + 8*SBK*256;            // 6*128
    int* cnt    = (int*)(yrows + 6*DD);
    int* inc    = cnt + NN;
    int* rowptr = inc + NN;                       // N+1
    int* cursor = rowptr + NN + 1;
    int* eidx   = cursor + NN;                    // E
    int* goff   = eidx + NE;                      // G+1
    int* bsum   = goff + GG + 1;

    float* out_pred   = out;
    float* out_hgraph = out + GG;
    float* out_hmeans = out + GG + GG*DD;

    const int E4_GRID   = (NE/4 + 255)/256;       // 586
    const int SETUP_GRID= (297041 + 255)/256;     // 1161
    const int GP_GRID   = GGRID + GG;             // 2075

    WPtrs wp;
    for (int i = 0; i < 3; i++){
        wp.p[i]   = linW + (size_t)i*DD*DD;
        wp.p[3+i] = W1   + (size_t)i*DD*DD;
        wp.p[6+i] = W2   + (size_t)i*DD*DD;
    }
    wp.p[9] = pW1; wp.p[10] = pW2;
    const ushort_t* WfLin = Wf;
    const ushort_t* WfW1  = Wf + 3*16384;
    const ushort_t* WfW2  = Wf + 6*16384;
    const ushort_t* WfPW1 = Wf + 9*16384;
    const ushort_t* WfPW2 = Wf + 10*16384;

    float* BK0 = SBANKS + 0*SBK*256;
    float* BK1 = SBANKS + 1*SBK*256;
    float* BK5 = SBANKS + 5*SBK*256;
    float* BK6 = SBANKS + 6*SBK*256;
    float* BK7 = SBANKS + 7*SBK*256;

    // setup + CSR (scanB folded into scanC)
    k_setup<<<SETUP_GRID, 256, 0, stream>>>(wp, Wf, bids, goff, cnt, SBANKS,
                                            emb, linW, linB, yrows);
    k_count<<<E4_GRID, 256, 0, stream>>>(dst, cnt);
    k_scanA<<<NB_SCAN, 512, 0, stream>>>(cnt, inc, bsum);
    k_scanC<<<NB_SCAN, 512, 0, stream>>>(cnt, inc, bsum, rowptr, cursor);
    k_fill<<<E4_GRID, 256, 0, stream>>>(src, dst, cursor, eidx);

    // ---- layer 0: fused LUT-gather W1-GEMM -> W2 GEMM ----
    k_gemm<4,0,1,0><<<GGRID, 256, 0, stream>>>(nullptr, WfW1, nullptr,
        nullptr, nullptr, nullptr,
        nullptr, rowptr, eidx, d, emb, yrows, epsA, 0,
        yb, BK0, nullptr, nullptr, NN);
    k_gemm<2,0,1,0><<<GGRID, 256, 0, stream>>>(yb, WfW2, nullptr, BK0, g1, b1,
        nullptr, nullptr, nullptr, nullptr, nullptr, nullptr, nullptr, 0,
        xb, BK1, nullptr, nullptr, NN);

    // ---- layers 1,2 ----
    for (int l = 1; l < LL; l++){
        float* pbank = SBANKS + (size_t)(2*l - 1)*SBK*256;
        float* bIn   = SBANKS + (size_t)(2*l)*SBK*256;
        float* bOut  = SBANKS + (size_t)(2*l + 1)*SBK*256;
        const float* pg = bng + (size_t)(l-1)*DD;
        const float* pb = bnb + (size_t)(l-1)*DD;

        // yb = relu(relu(bn(xb))@linW + bias); fused pool of prev layer's h_means
        k_gemm<2,1,0,1><<<GP_GRID, 256, 0, stream>>>(xb, WfLin + (size_t)l*16384,
            linB + (size_t)l*DD, pbank, pg, pb,
            nullptr, nullptr, nullptr, nullptr, nullptr, nullptr, nullptr, 0,
            yb, nullptr, goff, out_hmeans + (size_t)(l-1)*GG*DD, NN);
        // zb = [relu(bn(xb))*(1+eps) + gather(yb)] @ mlp_W1  (gather fused, +stats)
        k_gemm<3,0,1,0><<<GGRID, 256, 0, stream>>>(xb, WfW1 + (size_t)l*16384, nullptr,
            pbank, pg, pb,
            yb, rowptr, eidx, nullptr, nullptr, nullptr, epsA, l,
            zb, bIn, nullptr, nullptr, NN);
        // xb = relu(bn(zb)) @ mlp_W2  (+stats)
        k_gemm<2,0,1,0><<<GGRID, 256, 0, stream>>>(zb, WfW2 + (size_t)l*16384, nullptr,
            bIn, g1 + (size_t)l*DD, b1 + (size_t)l*DD,
            nullptr, nullptr, nullptr, nullptr, nullptr, nullptr, nullptr, 0,
            xb, bOut, nullptr, nullptr, NN);
    }

    // ---- pooling MLP (pW1-GEMM carries layer-2 h_means pool) ----
    k_gemm<2,0,1,1><<<GP_GRID, 256, 0, stream>>>(xb, WfPW1, nullptr,
        BK5, bng + 2*DD, bnb + 2*DD,
        nullptr, nullptr, nullptr, nullptr, nullptr, nullptr, nullptr, 0,
        yb, BK6, goff, out_hmeans + (size_t)2*GG*DD, NN);
    k_gemm<2,0,1,0><<<GGRID, 256, 0, stream>>>(yb, WfPW2, nullptr,
        BK6, pg1, pb1,
        nullptr, nullptr, nullptr, nullptr, nullptr, nullptr, nullptr, 0,
        zb, BK7, nullptr, nullptr, NN);
    // h_graph pool + predict (fused)
    k_poolpred<<<GG, 256, 0, stream>>>(zb, BK7, pbng, pbnb, goff,
        prW1, prb1, prW2, prb2, out_hgraph, out_pred);
}

// Round 20
// 352.030 us; speedup vs baseline: 3.4172x; 1.0171x over previous
//
#include <hip/hip_runtime.h>

typedef unsigned short ushort_t;
typedef __attribute__((ext_vector_type(8))) short bf16x8;
typedef __attribute__((ext_vector_type(4))) float f32x4;

#define NN 50000
#define NE 600000
#define DD 128
#define LL 3
#define GG 512
#define NB_SCAN 98   // ceil(NN/512)
#define GGRID 1563   // ceil(NN/32) gemm blocks (32 rows/block)
#define SBK 32       // stats banks

__device__ __forceinline__ float b2f(ushort_t u){ return __uint_as_float(((unsigned)u)<<16); }
__device__ __forceinline__ ushort_t f2b(float f){
    unsigned x = __float_as_uint(f);
    return (ushort_t)((x + 0x7fffu + ((x>>16)&1u)) >> 16);
}

// ---- marker for host-side input-layout mismatch (f32 out) ----
__global__ void k_mark(float* __restrict__ out, float val, int n){
    int i = blockIdx.x*256 + threadIdx.x; if (i >= n) return;
    out[i] = (i == 0) ? val : 0.f;
}

// ---- fused setup: wconv + goff + zero cnt + zero banks + layer-0 LUT ----
struct WPtrs { const float* p[11]; };
__global__ void k_setup(WPtrs wp, ushort_t* __restrict__ Wf,
                        const int* __restrict__ bids, int* __restrict__ goff,
                        int* __restrict__ cnt, float* __restrict__ banks,
                        const float* __restrict__ emb, const float* __restrict__ linW,
                        const float* __restrict__ linB, float* __restrict__ yrows){
    int idx = blockIdx.x*256 + threadIdx.x;
    if (idx < 180224){
        int m = idx >> 14, r = idx & 16383;
        int i = r & 7, l2 = (r >> 3) & 63, s = (r >> 9) & 3, n = r >> 11;
        int k   = s*32 + (l2 >> 4)*8 + i;
        int col = n*16 + (l2 & 15);
        Wf[idx] = f2b(wp.p[m][k*DD + col]);
    } else if (idx < 180737){
        int g = idx - 180224;            // 0..512
        int lo = 0, hi = NN;
        while (lo < hi){ int mid = (lo+hi) >> 1; if (bids[mid] < g) lo = mid+1; else hi = mid; }
        goff[g] = lo;
    } else if (idx < 230737){
        cnt[idx - 180737] = 0;
    } else if (idx < 296273){
        banks[idx - 230737] = 0.f;       // 8 instances * SBK * 256
    } else if (idx < 297041){
        int i = idx - 296273;            // 6*128
        int di = i >> 7, c = i & 127;
        float acc = linB[c];
        for (int k = 0; k < DD; k++) acc = fmaf(emb[di*DD + k], linW[k*DD + c], acc);
        yrows[i] = fmaxf(acc, 0.f);
    }
}

// ---------------- CSR: count (int4) ----------------
__global__ void k_count(const int* __restrict__ dst, int* __restrict__ cnt){
    int e4 = blockIdx.x*256 + threadIdx.x; if (e4 >= NE/4) return;
    int4 dv = ((const int4*)dst)[e4];
    atomicAdd(&cnt[dv.x], 1); atomicAdd(&cnt[dv.y], 1);
    atomicAdd(&cnt[dv.z], 1); atomicAdd(&cnt[dv.w], 1);
}
// ---------------- CSR: scanA ----------------
__global__ void k_scanA(const int* __restrict__ cnt, int* __restrict__ inc, int* __restrict__ bsum){
    __shared__ int s[512];
    int i = blockIdx.x*512 + threadIdx.x;
    int v = (i < NN) ? cnt[i] : 0;
    s[threadIdx.x] = v; __syncthreads();
    for (int off = 1; off < 512; off <<= 1){
        int add = (threadIdx.x >= off) ? s[threadIdx.x - off] : 0;
        __syncthreads();
        s[threadIdx.x] += add;
        __syncthreads();
    }
    if (i < NN) inc[i] = s[threadIdx.x];
    if (threadIdx.x == 511) bsum[blockIdx.x] = s[511];
}
// ---------------- CSR: scanC (block offset from bsum, in-block scan) ----------------
__global__ void k_scanC(const int* __restrict__ cnt, const int* __restrict__ inc,
                        const int* __restrict__ bsum, int* __restrict__ rowptr,
                        int* __restrict__ cursor){
    __shared__ int sb[128];
    int t = threadIdx.x;                 // 512
    if (t < 128) sb[t] = (t < NB_SCAN) ? bsum[t] : 0;
    __syncthreads();
    for (int off = 1; off < 128; off <<= 1){
        int a = (t < 128 && t >= off) ? sb[t - off] : 0;
        __syncthreads();
        if (t < 128) sb[t] += a;
        __syncthreads();
    }
    int myoff = (blockIdx.x == 0) ? 0 : sb[blockIdx.x - 1];
    int i = blockIdx.x*512 + t;
    if (i < NN){
        int e = myoff + inc[i] - cnt[i];
        rowptr[i] = e; cursor[i] = e;
    } else if (i == NN){
        rowptr[NN] = NE;
    }
}
// ---------------- CSR: fill (int4 loads) ----------------
__global__ void k_fill(const int* __restrict__ src, const int* __restrict__ dst,
                       int* __restrict__ cursor, int* __restrict__ eidx){
    int e4 = blockIdx.x*256 + threadIdx.x; if (e4 >= NE/4) return;
    int4 dv = ((const int4*)dst)[e4];
    int4 sv = ((const int4*)src)[e4];
    int p0 = atomicAdd(&cursor[dv.x], 1); eidx[p0] = sv.x;
    int p1 = atomicAdd(&cursor[dv.y], 1); eidx[p1] = sv.y;
    int p2 = atomicAdd(&cursor[dv.z], 1); eidx[p2] = sv.z;
    int p3 = atomicAdd(&cursor[dv.w], 1); eidx[p3] = sv.w;
}

// ---------------- MFMA GEMM: 32 rows x 128 cols, 4 waves, banked stats ----------------
// A-loads issued BEFORE the stats preamble so HBM latency overlaps bank-sum + barrier.
// AM: 0 plain | 2 relu(bn(A)) | 3 gather z=relu(bn(A))*(1+eps)+sum msg[src]
//     4 layer0 gather (LUTs in LDS).  OM: 0|1 relu(C+bias).  ST: stats -> bank atomic.
// POOL: blocks >= GGRID do graph-pool of A using banksIn.
template<int AM, int OM, int ST, int POOL>
__global__ __launch_bounds__(256) void k_gemm(
    const ushort_t* __restrict__ A, const ushort_t* __restrict__ Wf,
    const float* __restrict__ bias,
    const float* __restrict__ banksIn, const float* __restrict__ bng,
    const float* __restrict__ bnb,
    const ushort_t* __restrict__ msg,
    const int* __restrict__ rowptr, const int* __restrict__ eidx,
    const int* __restrict__ darr, const float* __restrict__ emb6,
    const float* __restrict__ yrows, const float* __restrict__ epsP, int lidx,
    ushort_t* __restrict__ C, float* __restrict__ banksOut,
    const int* __restrict__ goff, float* __restrict__ pool_out, int M)
{
    __shared__ float ssl[256];
    __shared__ float sred[256];
    __shared__ ushort_t lrep[32*132];
    __shared__ ushort_t zlds[(AM >= 3) ? 32*132 : 1];
    __shared__ float luts[(AM == 4) ? 2*6*132 : 1];   // yL | eL
    const int t = threadIdx.x;

    if (POOL && blockIdx.x >= GGRID){
        int g = blockIdx.x - GGRID;
        {
            float sv = 0.f;
#pragma unroll
            for (int b = 0; b < SBK; b++) sv += banksIn[(b << 8) + t];
            ssl[t] = sv;
        }
        __syncthreads();
        int c = t & 127, hf = t >> 7;
        float mu  = ssl[c] * (1.0f/NN);
        float var = ssl[c + DD] * (1.0f/NN) - mu*mu;
        float sc  = rsqrtf(fmaxf(var, 0.f) + 1e-5f) * bng[c];
        float sh  = bnb[c] - mu*sc;
        int r0 = goff[g], r1 = goff[g+1];
        float acc = 0.f;
        for (int r = r0 + hf; r < r1; r += 2)
            acc += fmaxf(fmaf(b2f(A[(size_t)r*DD + c]), sc, sh), 0.f);
        sred[t] = acc; __syncthreads();
        if (t < 128)
            pool_out[g*DD + t] = (sred[t] + sred[t+128]) / fmaxf((float)(r1 - r0), 1.0f);
        return;
    }

    const int w = t >> 6, l = t & 63;
    const int rw = w >> 1, cw = w & 1;
    const int rowBlk = blockIdx.x*32, rowBase = rowBlk + rw*16;
    const int lm = l & 15, kg = l >> 4;

    // ---- PREFETCH: issue independent global loads before the stats preamble ----
    bf16x8 pf[4];                  // A fragments (AM 0/2) or gather x-row halves (AM 3)
    int pe0 = 0, pe1 = 0;          // gather edge range (AM 3/4)
    int pdv = 0;                   // layer-0 own distance (AM 4)
    {
        if (AM == 0 || AM == 2){
            int arow = rowBase + lm; if (arow >= M) arow = M - 1;
            const ushort_t* ap = A + (size_t)arow*DD + kg*8;
#pragma unroll
            for (int s = 0; s < 4; s++) pf[s] = *(const bf16x8*)(ap + s*32);
        } else {
            int grow = rowBlk + (t >> 3); if (grow >= M) grow = M - 1;
            pe0 = rowptr[grow]; pe1 = rowptr[grow + 1];
            if (AM == 3){
                const ushort_t* xp = A + (size_t)grow*DD + (t & 7)*16;
                pf[0] = *(const bf16x8*)(xp);
                pf[1] = *(const bf16x8*)(xp + 8);
            } else {
                pdv = darr[grow]; pdv = pdv < 0 ? 0 : (pdv > 5 ? 5 : pdv);
            }
        }
    }

    if (AM == 2 || AM == 3){
        float sv = 0.f;
#pragma unroll
        for (int b = 0; b < SBK; b++) sv += banksIn[(b << 8) + t];
        ssl[t] = sv;
        __syncthreads();
        if (t < 128){
            float mu  = ssl[t] * (1.0f/NN);
            float var = ssl[t + DD] * (1.0f/NN) - mu*mu;
            float sc  = rsqrtf(fmaxf(var, 0.f) + 1e-5f) * bng[t];
            ssl[t] = sc;
            ssl[t + DD] = bnb[t] - mu*sc;
        }
    }
    if (AM == 4){
        for (int i = t; i < 6*DD; i += 256){
            int r6 = i >> 7, c = i & 127;
            luts[r6*132 + c]         = yrows[i];
            luts[6*132 + r6*132 + c] = emb6[i];
        }
    }
    if (ST) sred[t] = 0.f;
    __syncthreads();

    // ---- gather phase (AM 3/4): 8 threads/row build z in LDS ----
    if (AM == 3 || AM == 4){
        int row  = t >> 3;
        int cseg = (t & 7) * 16;
        float epl = 1.0f + epsP[lidx];
        float z[16];
        if (AM == 3){
#pragma unroll
            for (int i = 0; i < 8; i++){
                z[i]   = fmaxf(fmaf(b2f((ushort_t)pf[0][i]), ssl[cseg+i],   ssl[DD+cseg+i]),   0.f) * epl;
                z[8+i] = fmaxf(fmaf(b2f((ushort_t)pf[1][i]), ssl[cseg+8+i], ssl[DD+cseg+8+i]), 0.f) * epl;
            }
        } else {
            const float* ep = luts + 6*132 + pdv*132 + cseg;
#pragma unroll
            for (int i = 0; i < 16; i++) z[i] = ep[i] * epl;
        }
        if (AM == 3){
            int e = pe0;
            for (; e + 1 < pe1; e += 2){
                int s0 = eidx[e], s1 = eidx[e+1];
                const ushort_t* m0 = msg + (size_t)s0*DD + cseg;
                const ushort_t* m1 = msg + (size_t)s1*DD + cseg;
                bf16x8 a0 = *(const bf16x8*)(m0), a1 = *(const bf16x8*)(m0 + 8);
                bf16x8 b0 = *(const bf16x8*)(m1), b1 = *(const bf16x8*)(m1 + 8);
#pragma unroll
                for (int i = 0; i < 8; i++){
                    z[i]   += b2f((ushort_t)a0[i]) + b2f((ushort_t)b0[i]);
                    z[8+i] += b2f((ushort_t)a1[i]) + b2f((ushort_t)b1[i]);
                }
            }
            for (; e < pe1; e++){
                int s0 = eidx[e];
                const ushort_t* m0 = msg + (size_t)s0*DD + cseg;
                bf16x8 a0 = *(const bf16x8*)(m0), a1 = *(const bf16x8*)(m0 + 8);
#pragma unroll
                for (int i = 0; i < 8; i++){
                    z[i]   += b2f((ushort_t)a0[i]);
                    z[8+i] += b2f((ushort_t)a1[i]);
                }
            }
        } else {
            for (int e = pe0; e < pe1; e++){
                int di = darr[eidx[e]]; di = di < 0 ? 0 : (di > 5 ? 5 : di);
                const float* yp = luts + di*132 + cseg;
#pragma unroll
                for (int i = 0; i < 16; i++) z[i] += yp[i];
            }
        }
        ushort_t* zp = zlds + row*132 + cseg;
#pragma unroll
        for (int i = 0; i < 16; i++) zp[i] = f2b(z[i]);
        __syncthreads();
    }

    f32x4 acc[4];
#pragma unroll
    for (int n = 0; n < 4; n++) acc[n] = (f32x4){0.f,0.f,0.f,0.f};

    bf16x8 af[4];
    if (AM == 3 || AM == 4){
        const ushort_t* zp = zlds + (rw*16 + lm)*132 + kg*8;
#pragma unroll
        for (int s = 0; s < 4; s++) af[s] = *(const bf16x8*)(zp + s*32);
    } else if (AM == 0){
#pragma unroll
        for (int s = 0; s < 4; s++) af[s] = pf[s];
    } else {
#pragma unroll
        for (int s = 0; s < 4; s++){
            int k0 = s*32 + kg*8;
#pragma unroll
            for (int i = 0; i < 8; i++){
                float v = b2f((ushort_t)pf[s][i]);
                v = fmaxf(fmaf(v, ssl[k0+i], ssl[DD+k0+i]), 0.f);
                ((ushort_t*)&af[s])[i] = f2b(v);
            }
        }
    }

#pragma unroll
    for (int s = 0; s < 4; s++){
#pragma unroll
        for (int n = 0; n < 4; n++){
            int nc = cw*4 + n;
            bf16x8 bfr = *(const bf16x8*)(Wf + (size_t)((nc*4 + s)*64 + l)*8);
            acc[n] = __builtin_amdgcn_mfma_f32_16x16x32_bf16(af[s], bfr, acc[n], 0, 0, 0);
        }
    }

    // transform + stats + bf16 LDS repack
#pragma unroll
    for (int n = 0; n < 4; n++){
        int col = (cw*4 + n)*16 + lm;
        float cs = 0.f, cq = 0.f;
#pragma unroll
        for (int j = 0; j < 4; j++){
            float v = acc[n][j];
            if (OM == 1) v = fmaxf(v + bias[col], 0.f);
            lrep[(rw*16 + kg*4 + j)*132 + col] = f2b(v);
            if (ST && (rowBase + kg*4 + j) < M){ cs += v; cq += v*v; }
        }
        if (ST){
            cs += __shfl_xor(cs, 16); cs += __shfl_xor(cs, 32);
            cq += __shfl_xor(cq, 16); cq += __shfl_xor(cq, 32);
            if (kg == 0){
                atomicAdd(&sred[col], cs);
                atomicAdd(&sred[col + DD], cq);
            }
        }
    }
    __syncthreads();

    // coalesced store
    {
        int lr = t >> 3;
        int gr = rowBlk + lr;
        if (gr < M){
            int seg = (t & 7) * 16;
            const ushort_t* lp = lrep + lr*132 + seg;
            bf16x8 o0 = *(const bf16x8*)(lp);
            bf16x8 o1 = *(const bf16x8*)(lp + 8);
            ushort_t* cp = C + (size_t)gr*DD + seg;
            *(bf16x8*)(cp)     = o0;
            *(bf16x8*)(cp + 8) = o1;
        }
    }

    if (ST){
        __syncthreads();
        atomicAdd(&banksOut[((blockIdx.x & (SBK-1)) << 8) + t], sred[t]);
    }
}

// ---------------- fused h_graph pool + predict head (banked stats in) ----------------
__global__ __launch_bounds__(256) void k_poolpred(const ushort_t* __restrict__ zb,
        const float* __restrict__ banksIn, const float* __restrict__ bng,
        const float* __restrict__ bnb, const int* __restrict__ goff,
        const float* __restrict__ W1, const float* __restrict__ b1,
        const float* __restrict__ W2, const float* __restrict__ b2,
        float* __restrict__ out_hgraph, float* __restrict__ out_pred){
    __shared__ float hrow[DD];
    __shared__ float pr[256];
    int g = blockIdx.x, t = threadIdx.x;
    {
        float sv = 0.f;
#pragma unroll
        for (int b = 0; b < SBK; b++) sv += banksIn[(b << 8) + t];
        pr[t] = sv;
    }
    __syncthreads();
    int c = t & 127, hf = t >> 7;
    float mu  = pr[c] * (1.0f/NN);
    float var = pr[c + DD] * (1.0f/NN) - mu*mu;
    float sc  = rsqrtf(fmaxf(var, 0.f) + 1e-5f) * bng[c];
    float sh  = bnb[c] - mu*sc;
    __syncthreads();
    int r0 = goff[g], r1 = goff[g+1];
    float acc = 0.f;
    for (int r = r0 + hf; r < r1; r += 2)
        acc += fmaxf(fmaf(b2f(zb[(size_t)r*DD + c]), sc, sh), 0.f);
    pr[t] = acc; __syncthreads();
    if (t < 128){
        float m = (pr[t] + pr[t+128]) / fmaxf((float)(r1 - r0), 1.0f);
        hrow[t] = m;
        out_hgraph[g*DD + t] = m;
    }
    __syncthreads();
    float a2 = b1[t];
    for (int k = 0; k < DD; k++) a2 = fmaf(hrow[k], W1[k*256 + t], a2);
    pr[t] = fmaxf(a2, 0.f) * W2[t];
    __syncthreads();
    for (int off = 128; off > 0; off >>= 1){
        if (t < off) pr[t] += pr[t + off];
        __syncthreads();
    }
    if (t == 0) out_pred[g] = pr[0] + b2[0];
}

extern "C" void kernel_launch(void* const* d_in, const int* in_sizes, int n_in,
                              void* d_out, int out_size, void* d_ws, size_t ws_size,
                              hipStream_t stream){
    float* out = (float*)d_out;
    const int OUT_N = GG + GG*DD + LL*GG*DD;      // 262656

    static const int EXP[24] = {50000,600000,600000,50000, 768,49152,384,49152,384,384,
                                49152,3,384,384,16384,128,128,16384,128,128,
                                32768,256,256,1};
    int bad = -1;
    if (n_in != 24) bad = 50;
    else for (int i = 0; i < 24; i++) if (in_sizes[i] != EXP[i]) { bad = i; break; }
    if (bad >= 0){
        k_mark<<<(OUT_N+255)/256, 256, 0, stream>>>(out, 2048.0f + (float)bad, OUT_N);
        return;
    }

    const int* d    = (const int*)d_in[0];
    const int* src  = (const int*)d_in[1];
    const int* dst  = (const int*)d_in[2];
    const int* bids = (const int*)d_in[3];
    const float* emb  = (const float*)d_in[4];
    const float* linW = (const float*)d_in[5];
    const float* linB = (const float*)d_in[6];
    const float* W1   = (const float*)d_in[7];
    const float* g1   = (const float*)d_in[8];
    const float* b1   = (const float*)d_in[9];
    const float* W2   = (const float*)d_in[10];
    const float* epsA = (const float*)d_in[11];
    const float* bng  = (const float*)d_in[12];
    const float* bnb  = (const float*)d_in[13];
    const float* pW1  = (const float*)d_in[14];
    const float* pg1  = (const float*)d_in[15];
    const float* pb1  = (const float*)d_in[16];
    const float* pW2  = (const float*)d_in[17];
    const float* pbng = (const float*)d_in[18];
    const float* pbnb = (const float*)d_in[19];
    const float* prW1 = (const float*)d_in[20];
    const float* prb1 = (const float*)d_in[21];
    const float* prW2 = (const float*)d_in[22];
    const float* prb2 = (const float*)d_in[23];

    // ---- workspace ----
    ushort_t* xb  = (ushort_t*)d_ws;
    ushort_t* yb  = xb + (size_t)NN*DD;
    ushort_t* zb  = yb + (size_t)NN*DD;
    ushort_t* Wf  = zb + (size_t)NN*DD;           // 11*16384 bf16
    float* SBANKS= (float*)(Wf + 11*16384);       // 8 * SBK * 256
    float* yrows = SBANKS + 8*SBK*256;            // 6*128
    int* cnt    = (int*)(yrows + 6*DD);
    int* inc    = cnt + NN;
    int* rowptr = inc + NN;                       // N+1
    int* cursor = rowptr + NN + 1;
    int* eidx   = cursor + NN;                    // E
    int* goff   = eidx + NE;                      // G+1
    int* bsum   = goff + GG + 1;

    float* out_pred   = out;
    float* out_hgraph = out + GG;
    float* out_hmeans = out + GG + GG*DD;

    const int E4_GRID   = (NE/4 + 255)/256;       // 586
    const int SETUP_GRID= (297041 + 255)/256;     // 1161
    const int GP_GRID   = GGRID + GG;             // 2075

    WPtrs wp;
    for (int i = 0; i < 3; i++){
        wp.p[i]   = linW + (size_t)i*DD*DD;
        wp.p[3+i] = W1   + (size_t)i*DD*DD;
        wp.p[6+i] = W2   + (size_t)i*DD*DD;
    }
    wp.p[9] = pW1; wp.p[10] = pW2;
    const ushort_t* WfLin = Wf;
    const ushort_t* WfW1  = Wf + 3*16384;
    const ushort_t* WfW2  = Wf + 6*16384;
    const ushort_t* WfPW1 = Wf + 9*16384;
    const ushort_t* WfPW2 = Wf + 10*16384;

    float* BK0 = SBANKS + 0*SBK*256;
    float* BK1 = SBANKS + 1*SBK*256;
    float* BK5 = SBANKS + 5*SBK*256;
    float* BK6 = SBANKS + 6*SBK*256;
    float* BK7 = SBANKS + 7*SBK*256;

    // setup + CSR
    k_setup<<<SETUP_GRID, 256, 0, stream>>>(wp, Wf, bids, goff, cnt, SBANKS,
                                            emb, linW, linB, yrows);
    k_count<<<E4_GRID, 256, 0, stream>>>(dst, cnt);
    k_scanA<<<NB_SCAN, 512, 0, stream>>>(cnt, inc, bsum);
    k_scanC<<<NB_SCAN, 512, 0, stream>>>(cnt, inc, bsum, rowptr, cursor);
    k_fill<<<E4_GRID, 256, 0, stream>>>(src, dst, cursor, eidx);

    // ---- layer 0: fused LUT-gather W1-GEMM -> W2 GEMM ----
    k_gemm<4,0,1,0><<<GGRID, 256, 0, stream>>>(nullptr, WfW1, nullptr,
        nullptr, nullptr, nullptr,
        nullptr, rowptr, eidx, d, emb, yrows, epsA, 0,
        yb, BK0, nullptr, nullptr, NN);
    k_gemm<2,0,1,0><<<GGRID, 256, 0, stream>>>(yb, WfW2, nullptr, BK0, g1, b1,
        nullptr, nullptr, nullptr, nullptr, nullptr, nullptr, nullptr, 0,
        xb, BK1, nullptr, nullptr, NN);

    // ---- layers 1,2 ----
    for (int l = 1; l < LL; l++){
        float* pbank = SBANKS + (size_t)(2*l - 1)*SBK*256;
        float* bIn   = SBANKS + (size_t)(2*l)*SBK*256;
        float* bOut  = SBANKS + (size_t)(2*l + 1)*SBK*256;
        const float* pg = bng + (size_t)(l-1)*DD;
        const float* pb = bnb + (size_t)(l-1)*DD;

        k_gemm<2,1,0,1><<<GP_GRID, 256, 0, stream>>>(xb, WfLin + (size_t)l*16384,
            linB + (size_t)l*DD, pbank, pg, pb,
            nullptr, nullptr, nullptr, nullptr, nullptr, nullptr, nullptr, 0,
            yb, nullptr, goff, out_hmeans + (size_t)(l-1)*GG*DD, NN);
        k_gemm<3,0,1,0><<<GGRID, 256, 0, stream>>>(xb, WfW1 + (size_t)l*16384, nullptr,
            pbank, pg, pb,
            yb, rowptr, eidx, nullptr, nullptr, nullptr, epsA, l,
            zb, bIn, nullptr, nullptr, NN);
        k_gemm<2,0,1,0><<<GGRID, 256, 0, stream>>>(zb, WfW2 + (size_t)l*16384, nullptr,
            bIn, g1 + (size_t)l*DD, b1 + (size_t)l*DD,
            nullptr, nullptr, nullptr, nullptr, nullptr, nullptr, nullptr, 0,
            xb, bOut, nullptr, nullptr, NN);
    }

    // ---- pooling MLP (pW1-GEMM carries layer-2 h_means pool) ----
    k_gemm<2,0,1,1><<<GP_GRID, 256, 0, stream>>>(xb, WfPW1, nullptr,
        BK5, bng + 2*DD, bnb + 2*DD,
        nullptr, nullptr, nullptr, nullptr, nullptr, nullptr, nullptr, 0,
        yb, BK6, goff, out_hmeans + (size_t)2*GG*DD, NN);
    k_gemm<2,0,1,0><<<GGRID, 256, 0, stream>>>(yb, WfPW2, nullptr,
        BK6, pg1, pb1,
        nullptr, nullptr, nullptr, nullptr, nullptr, nullptr, nullptr, 0,
        zb, BK7, nullptr, nullptr, NN);
    // h_graph pool + predict (fused)
    k_poolpred<<<GG, 256, 0, stream>>>(zb, BK7, pbng, pbnb, goff,
        prW1, prb1, prW2, prb2, out_hgraph, out_pred);
}